// Round 5
// baseline (1196.715 us; speedup 1.0000x reference)
//
#include <hip/hip_runtime.h>
#include <stdint.h>

#define T_LEN 256
#define BATCH 64
#define EDIM  512
#define HDIM  256      // hidden per direction
#define GDIM  1024     // 4*HDIM
#define KTAG  7
#define NEGV  -10000.0f

using u16 = unsigned short;
using u32 = unsigned int;
using u64 = unsigned long long;

typedef short    bf16x8 __attribute__((ext_vector_type(8)));
typedef float    f32x4  __attribute__((ext_vector_type(4)));

__device__ __forceinline__ float bflo(u32 u) { return __uint_as_float(u << 16); }
__device__ __forceinline__ float bfhi(u32 u) { return __uint_as_float(u & 0xffff0000u); }
__device__ __forceinline__ float bf2f(u16 u) { return __uint_as_float(((u32)u) << 16); }
__device__ __forceinline__ u16 f2bf(float f) {
    u32 x = __float_as_uint(f);
    u32 r = x + 0x7fffu + ((x >> 16) & 1u);   // round-to-nearest-even
    return (u16)(r >> 16);
}
__device__ __forceinline__ u32 pack2(float a, float b) {
    return (u32)f2bf(a) | ((u32)f2bf(b) << 16);
}
// fast sigmoid / tanh (rel err ~1e-5, far below bf16 input noise)
__device__ __forceinline__ float fsig(float x)  { return __builtin_amdgcn_rcpf(1.f + __expf(-x)); }
__device__ __forceinline__ float ftanh(float x) { return 1.f - 2.f * __builtin_amdgcn_rcpf(1.f + __expf(2.f * x)); }

__device__ __forceinline__ int dot4i8(int a, int b, int c) {
#if __has_builtin(__builtin_amdgcn_sdot4)
    return __builtin_amdgcn_sdot4(a, b, c, false);     // v_dot4_i32_i8
#else
    c += (int)(signed char)(a & 0xff)         * (int)(signed char)(b & 0xff);
    c += (int)(signed char)((a >> 8) & 0xff)  * (int)(signed char)((b >> 8) & 0xff);
    c += (int)(signed char)((a >> 16) & 0xff) * (int)(signed char)((b >> 16) & 0xff);
    c += (int)(signed char)(a >> 24)          * (int)(signed char)(b >> 24);
    return c;
#endif
}

// light barrier: order LDS only; global loads/stores stay in flight (no vmcnt drain)
__device__ __forceinline__ void bar_lds() {
    asm volatile("s_waitcnt lgkmcnt(0)" ::: "memory");
    __builtin_amdgcn_s_barrier();
    asm volatile("" ::: "memory");
}

// async global->LDS, 16B per lane; LDS dest must be linear (base + lane*16)
__device__ __forceinline__ void gload_lds16(const void* g, void* l) {
    __builtin_amdgcn_global_load_lds((const __attribute__((address_space(1))) u32*)g,
                                     (__attribute__((address_space(3))) u32*)l, 16, 0, 0);
}

// ---------------- embedding gather+convert: x[tb][e] = bf16(emb[sent[tb]][e]) ----------------
__global__ __launch_bounds__(64) void embed_k(const int* __restrict__ sent,
                                              const float* __restrict__ emb,
                                              u16* __restrict__ X) {
    int tb = blockIdx.x;
    int tok = sent[tb];
    const float4* src = (const float4*)(emb + (size_t)tok * EDIM);
    float4 a = src[threadIdx.x * 2];
    float4 b = src[threadIdx.x * 2 + 1];
    uint4 o;
    o.x = pack2(a.x, a.y); o.y = pack2(a.z, a.w);
    o.z = pack2(b.x, b.y); o.w = pack2(b.z, b.w);
    ((uint4*)(X + (size_t)tb * EDIM))[threadIdx.x] = o;
}

// ---------------- convert w_ih f32 -> bf16, same layout [2][2][1024][512] ----------------
__global__ __launch_bounds__(256) void conv_wih(const float* __restrict__ W,
                                                u16* __restrict__ WB) {
    int g = blockIdx.x * 256 + threadIdx.x;          // 262144 groups of 8
    const float4* src = (const float4*)(W + (size_t)g * 8);
    float4 a = src[0], b = src[1];
    uint4 o;
    o.x = pack2(a.x, a.y); o.y = pack2(a.z, a.w);
    o.z = pack2(b.x, b.y); o.w = pack2(b.z, b.w);
    *(uint4*)(WB + (size_t)g * 8) = o;
}

// ---- quantize w_hh f32 [4][1024][256] -> int8 WQ[((ld*4+r)*16 + c8)*256 + j] uint4 + SCL ----
// chunk c8 (0..15) of row holds k = c8*16 .. c8*16+16.  SCL[ld*1024+row] = rowmax/127.
__global__ __launch_bounds__(256) void repack_whh_i8(const float* __restrict__ Whh,
                                                     uint4* __restrict__ WQ,
                                                     float* __restrict__ SCL) {
    int g  = blockIdx.x * 256 + threadIdx.x;    // 4096 rows
    int ld = g >> 10, row = g & 1023;
    const float* src = Whh + ((size_t)ld * GDIM + row) * HDIM;
    float m = 1e-30f;
    for (int k4 = 0; k4 < 64; ++k4) {
        float4 w = ((const float4*)src)[k4];
        m = fmaxf(m, fmaxf(fmaxf(fabsf(w.x), fabsf(w.y)), fmaxf(fabsf(w.z), fabsf(w.w))));
    }
    float inv = 127.f / m;
    SCL[ld * GDIM + row] = m / 127.f;
    int r = row >> 8, j = row & 255;
    for (int c8 = 0; c8 < 16; ++c8) {           // 16-byte chunks
        u32 dw[4];
        #pragma unroll
        for (int d4 = 0; d4 < 4; ++d4) {
            u32 p = 0;
            #pragma unroll
            for (int bb = 0; bb < 4; ++bb) {
                float w = src[c8 * 16 + d4 * 4 + bb];
                int q = (int)rintf(w * inv);
                q = q > 127 ? 127 : (q < -127 ? -127 : q);
                p |= ((u32)(q & 0xff)) << (8 * bb);
            }
            dw[d4] = p;
        }
        WQ[(size_t)(((ld * 4 + r) * 16 + c8) * 256 + j)] =
            (uint4){dw[0], dw[1], dw[2], dw[3]};
    }
}

// ------------- xg = x @ w_ih^T + b_ih + b_hh -------------
// 128x128 tile, BK=64, double-buffered gload_lds staging, 2-phase pipeline.
__global__ __launch_bounds__(256, 2) void gemm_xg(const u16* __restrict__ A,    // [16384][512] bf16
                                                  const u16* __restrict__ W,    // [2][1024][512] bf16
                                                  const float* __restrict__ Bih,// [2][1024] f32
                                                  const float* __restrict__ Bhh,
                                                  u16* __restrict__ XG) {       // [2][16384][1024] bf16
    const int d    = blockIdx.z;
    const int brow = blockIdx.x;               // 0..127 (M tiles)
    const int bcol = blockIdx.y;               // 0..7   (N tiles)
    const int tid  = threadIdx.x;
    const int lane = tid & 63;
    const int wv   = tid >> 6;                 // 4 waves: 2x2 of 64x64
    const int l15  = lane & 15;
    const int quad = lane >> 4;
    const int wr   = wv >> 1, wc = wv & 1;

    __shared__ u16 As[2][128 * 64];            // 2 x 16 KB, linear (gload_lds dest)
    __shared__ u16 Bs[2][128 * 64];            // 2 x 16 KB

    const u16* Wd = W + (size_t)d * GDIM * EDIM;
    const int srow = tid >> 3;                 // staging: 32 rows / issue
    const int scol = (tid & 7) * 8;            // u16 units (16 B per lane)
    const u16* ga = A  + (size_t)(brow * 128 + srow) * EDIM + scol;
    const u16* gb = Wd + (size_t)(bcol * 128 + srow) * EDIM + scol;
    const int loff = srow * 64 + scol;

    f32x4 acc[4][4];
    #pragma unroll
    for (int mt = 0; mt < 4; ++mt)
        #pragma unroll
        for (int nt = 0; nt < 4; ++nt)
            acc[mt][nt] = (f32x4){0.f, 0.f, 0.f, 0.f};

    // prologue: stage tile 0
    #pragma unroll
    for (int it = 0; it < 4; ++it) {
        gload_lds16(ga + (size_t)(it * 32) * EDIM, &As[0][loff + it * 32 * 64]);
        gload_lds16(gb + (size_t)(it * 32) * EDIM, &Bs[0][loff + it * 32 * 64]);
    }
    __syncthreads();

    int cur = 0;
    for (int t = 0; t < 8; ++t) {
        if (t < 7) {                           // issue next tile into other buffer
            int k0 = (t + 1) * 64;
            #pragma unroll
            for (int it = 0; it < 4; ++it) {
                gload_lds16(ga + (size_t)(it * 32) * EDIM + k0, &As[cur ^ 1][loff + it * 32 * 64]);
                gload_lds16(gb + (size_t)(it * 32) * EDIM + k0, &Bs[cur ^ 1][loff + it * 32 * 64]);
            }
        }
        const u16* Ab = As[cur];
        const u16* Bb = Bs[cur];
        #pragma unroll
        for (int ks = 0; ks < 2; ++ks) {
            bf16x8 av[4], bv[4];
            #pragma unroll
            for (int mt = 0; mt < 4; ++mt)
                av[mt] = *(const bf16x8*)(Ab + (wr * 64 + mt * 16 + l15) * 64 + ks * 32 + quad * 8);
            #pragma unroll
            for (int nt = 0; nt < 4; ++nt)
                bv[nt] = *(const bf16x8*)(Bb + (wc * 64 + nt * 16 + l15) * 64 + ks * 32 + quad * 8);
            #pragma unroll
            for (int mt = 0; mt < 4; ++mt)
                #pragma unroll
                for (int nt = 0; nt < 4; ++nt)
                    acc[mt][nt] = __builtin_amdgcn_mfma_f32_16x16x32_bf16(av[mt], bv[nt], acc[mt][nt], 0, 0, 0);
        }
        __syncthreads();                       // drains vmcnt: next tile ready, reads done
        cur ^= 1;
    }

    u16* xgd = XG + (size_t)d * ((size_t)16384 * GDIM);
    #pragma unroll
    for (int nt = 0; nt < 4; ++nt) {
        int col = bcol * 128 + wc * 64 + nt * 16 + l15;   // C/D: col=lane&15, row=quad*4+reg
        float bias = Bih[d * GDIM + col] + Bhh[d * GDIM + col];
        #pragma unroll
        for (int mt = 0; mt < 4; ++mt) {
            int row0 = brow * 128 + wr * 64 + mt * 16 + quad * 4;
            #pragma unroll
            for (int r = 0; r < 4; ++r)
                xgd[(size_t)(row0 + r) * GDIM + col] = f2bf(acc[mt][nt][r] + bias);
        }
    }
}

// ------------- recurrent scan: int8 weights pinned in AGPRs -------------
// 128 blocks = (d,b); 1024 threads: j = tid&255, q = tid>>8 (K-quarter).
// R1-R4 post-mortem: every allocator-level attempt (launch_bounds, waves_per_eu,
// asm pins) left VGPR_Count at 56-60 -> the 64 weight dwords/thread were being
// re-fetched from L2/scratch every step. 256 KB/block/step through the CU's
// ~110 B/cyc vector-memory return path = ~2300 cyc/step = the entire observed
// step time (invariant across R1-R4 because scratch and WQ cost the same).
// Weights can never be L1-resident (256 KB >> 32 KB L1), so the ONLY fix is
// register residency. gfx950's unified VGPR/AGPR file: we pin the 64 dwords in
// AGPRs with EXPLICIT v_accvgpr_write (once) / v_accvgpr_read (per use) via the
// "a" inline-asm constraint - instructions the compiler cannot sink or elide.
// Budget: 64 AGPR + ~60 VGPR = ~124 <= 128 (hard cap for 1024-thr blocks).
// Integer add order per accumulator chain unchanged -> bit-identical output.
#define LDW(r, c, n0, n1, n2, n3) do {                                              \
    uint4 t_ = WQ[(size_t)(((d * 4 + (r)) * 16 + q * 4 + (c)) * 256 + j)];          \
    asm volatile("v_accvgpr_write_b32 %0, %1" : "=a"(Wa##n0) : "v"(t_.x));          \
    asm volatile("v_accvgpr_write_b32 %0, %1" : "=a"(Wa##n1) : "v"(t_.y));          \
    asm volatile("v_accvgpr_write_b32 %0, %1" : "=a"(Wa##n2) : "v"(t_.z));          \
    asm volatile("v_accvgpr_write_b32 %0, %1" : "=a"(Wa##n3) : "v"(t_.w));          \
  } while (0)
#define DOTA(acc, n, h) do { u32 tw_;                                               \
    asm volatile("v_accvgpr_read_b32 %0, %1" : "=v"(tw_) : "a"(Wa##n));             \
    acc = dot4i8((int)tw_, (int)(h), acc);                                          \
  } while (0)

__global__ __attribute__((amdgpu_waves_per_eu(4, 4))) __launch_bounds__(1024)
void lstm_scan_i8(
        const u16* __restrict__ XG,        // [2][16384][1024] bf16 (this layer)
        const uint4* __restrict__ WQ,      // this layer's int8 slice
        const float* __restrict__ SCL,     // [2][1024] weight LSB
        const float* __restrict__ H0,      // [2][64][256] f32
        const float* __restrict__ C0,
        u16* __restrict__ XOUT) {          // [16384][512] bf16
    const int b   = blockIdx.x & 63;
    const int d   = blockIdx.x >> 6;
    const int tid = threadIdx.x;
    const int j   = tid & 255;
    const int q   = tid >> 8;              // K-quarter 0..3

    __shared__ uint4  hq[2][16];           // double-buffered int8 h (2 x 256 B)
    __shared__ float4 psv[4 * 256];        // per-quarter integer partials (exact f32), 16 KB

    // ---- 64 weight dwords, AGPR-resident for the whole scan ----
    u32 Wa0,  Wa1,  Wa2,  Wa3,  Wa4,  Wa5,  Wa6,  Wa7;
    u32 Wa8,  Wa9,  Wa10, Wa11, Wa12, Wa13, Wa14, Wa15;
    u32 Wa16, Wa17, Wa18, Wa19, Wa20, Wa21, Wa22, Wa23;
    u32 Wa24, Wa25, Wa26, Wa27, Wa28, Wa29, Wa30, Wa31;
    u32 Wa32, Wa33, Wa34, Wa35, Wa36, Wa37, Wa38, Wa39;
    u32 Wa40, Wa41, Wa42, Wa43, Wa44, Wa45, Wa46, Wa47;
    u32 Wa48, Wa49, Wa50, Wa51, Wa52, Wa53, Wa54, Wa55;
    u32 Wa56, Wa57, Wa58, Wa59, Wa60, Wa61, Wa62, Wa63;

    LDW(0, 0,  0,  1,  2,  3);  LDW(0, 1,  4,  5,  6,  7);
    LDW(0, 2,  8,  9, 10, 11);  LDW(0, 3, 12, 13, 14, 15);
    LDW(1, 0, 16, 17, 18, 19);  LDW(1, 1, 20, 21, 22, 23);
    LDW(1, 2, 24, 25, 26, 27);  LDW(1, 3, 28, 29, 30, 31);
    LDW(2, 0, 32, 33, 34, 35);  LDW(2, 1, 36, 37, 38, 39);
    LDW(2, 2, 40, 41, 42, 43);  LDW(2, 3, 44, 45, 46, 47);
    LDW(3, 0, 48, 49, 50, 51);  LDW(3, 1, 52, 53, 54, 55);
    LDW(3, 2, 56, 57, 58, 59);  LDW(3, 3, 60, 61, 62, 63);

    float scl0 = 0.f, scl1 = 0.f, scl2 = 0.f, scl3 = 0.f, cst = 0.f;
    if (q == 0) {
        scl0 = SCL[d * GDIM + 0 * 256 + j];
        scl1 = SCL[d * GDIM + 1 * 256 + j];
        scl2 = SCL[d * GDIM + 2 * 256 + j];
        scl3 = SCL[d * GDIM + 3 * 256 + j];
        float h0v = H0[((size_t)d * BATCH + b) * HDIM + j];
        cst       = C0[((size_t)d * BATCH + b) * HDIM + j];
        int qz = (int)rintf(h0v * 31.75f);                 // scale 127/4 (|h0| can exceed 1)
        qz = qz > 127 ? 127 : (qz < -127 ? -127 : qz);
        ((signed char*)hq)[j] = (signed char)qz;           // buffer 0
    }
    __syncthreads();

    const u16* xgp = XG + (size_t)d * ((size_t)16384 * GDIM) + (size_t)b * GDIM + j;
    // even/odd register pipeline: xe used at even steps, xo at odd; reload 2 steps ahead
    u16 xe[4], xo[4];
    if (q == 0) {
        int t0 = d ? T_LEN - 1 : 0;
        int t1 = d ? T_LEN - 2 : 1;
        #pragma unroll
        for (int r = 0; r < 4; ++r) xe[r] = xgp[(size_t)t0 * (BATCH * GDIM) + r * 256];
        #pragma unroll
        for (int r = 0; r < 4; ++r) xo[r] = xgp[(size_t)t1 * (BATCH * GDIM) + r * 256];
    }

    float hs = 4.f / 127.f;                // h LSB for step 0 input h; 1/127 afterwards

#define SCAN_SUBSTEP(S, XA, RB, WB)                                                     \
    {                                                                                   \
        const int t_ = d ? (T_LEN - 1 - (S)) : (S);                                     \
        const uint4* hb = (const uint4*)hq + (RB) * 16 + q * 4;                         \
        uint4 hv[4];                                                                    \
        _Pragma("unroll")                                                               \
        for (int c = 0; c < 4; ++c) hv[c] = hb[c];          /* wave-uniform: broadcast */\
        int a0 = 0, a1 = 0, a2 = 0, a3 = 0;                                             \
        DOTA(a0,  0, hv[0].x); DOTA(a1, 16, hv[0].x); DOTA(a2, 32, hv[0].x); DOTA(a3, 48, hv[0].x); \
        DOTA(a0,  1, hv[0].y); DOTA(a1, 17, hv[0].y); DOTA(a2, 33, hv[0].y); DOTA(a3, 49, hv[0].y); \
        DOTA(a0,  2, hv[0].z); DOTA(a1, 18, hv[0].z); DOTA(a2, 34, hv[0].z); DOTA(a3, 50, hv[0].z); \
        DOTA(a0,  3, hv[0].w); DOTA(a1, 19, hv[0].w); DOTA(a2, 35, hv[0].w); DOTA(a3, 51, hv[0].w); \
        DOTA(a0,  4, hv[1].x); DOTA(a1, 20, hv[1].x); DOTA(a2, 36, hv[1].x); DOTA(a3, 52, hv[1].x); \
        DOTA(a0,  5, hv[1].y); DOTA(a1, 21, hv[1].y); DOTA(a2, 37, hv[1].y); DOTA(a3, 53, hv[1].y); \
        DOTA(a0,  6, hv[1].z); DOTA(a1, 22, hv[1].z); DOTA(a2, 38, hv[1].z); DOTA(a3, 54, hv[1].z); \
        DOTA(a0,  7, hv[1].w); DOTA(a1, 23, hv[1].w); DOTA(a2, 39, hv[1].w); DOTA(a3, 55, hv[1].w); \
        DOTA(a0,  8, hv[2].x); DOTA(a1, 24, hv[2].x); DOTA(a2, 40, hv[2].x); DOTA(a3, 56, hv[2].x); \
        DOTA(a0,  9, hv[2].y); DOTA(a1, 25, hv[2].y); DOTA(a2, 41, hv[2].y); DOTA(a3, 57, hv[2].y); \
        DOTA(a0, 10, hv[2].z); DOTA(a1, 26, hv[2].z); DOTA(a2, 42, hv[2].z); DOTA(a3, 58, hv[2].z); \
        DOTA(a0, 11, hv[2].w); DOTA(a1, 27, hv[2].w); DOTA(a2, 43, hv[2].w); DOTA(a3, 59, hv[2].w); \
        DOTA(a0, 12, hv[3].x); DOTA(a1, 28, hv[3].x); DOTA(a2, 44, hv[3].x); DOTA(a3, 60, hv[3].x); \
        DOTA(a0, 13, hv[3].y); DOTA(a1, 29, hv[3].y); DOTA(a2, 45, hv[3].y); DOTA(a3, 61, hv[3].y); \
        DOTA(a0, 14, hv[3].z); DOTA(a1, 30, hv[3].z); DOTA(a2, 46, hv[3].z); DOTA(a3, 62, hv[3].z); \
        DOTA(a0, 15, hv[3].w); DOTA(a1, 31, hv[3].w); DOTA(a2, 47, hv[3].w); DOTA(a3, 63, hv[3].w); \
        /* |quarter partial| < 2^21 -> f32-exact; sums of 4 stay < 2^24 -> exact */     \
        psv[q * 256 + j] = (float4){(float)a0, (float)a1, (float)a2, (float)a3};        \
        bar_lds();                                                                      \
        if (q == 0) {                                                                   \
            float4 p0 = psv[j], p1 = psv[256 + j], p2 = psv[512 + j], p3 = psv[768 + j];\
            float g0 = bf2f(XA[0]) + (p0.x + p1.x + p2.x + p3.x) * (scl0 * hs);         \
            float g1 = bf2f(XA[1]) + (p0.y + p1.y + p2.y + p3.y) * (scl1 * hs);         \
            float g2 = bf2f(XA[2]) + (p0.z + p1.z + p2.z + p3.z) * (scl2 * hs);         \
            float g3 = bf2f(XA[3]) + (p0.w + p1.w + p2.w + p3.w) * (scl3 * hs);         \
            float iv = fsig(g0), fv = fsig(g1), gv = ftanh(g2), ov = fsig(g3);          \
            cst = fv * cst + iv * gv;                                                   \
            float h = ov * ftanh(cst);                                                  \
            XOUT[((size_t)t_ * BATCH + b) * EDIM + d * HDIM + j] = f2bf(h);             \
            int qz = (int)rintf(h * 127.f);                /* |h|<1: scale 1/127 */     \
            qz = qz > 127 ? 127 : (qz < -127 ? -127 : qz);                              \
            ((signed char*)hq)[(WB) * 256 + j] = (signed char)qz;                       \
            int s2 = ((S) + 2 < T_LEN) ? (S) + 2 : T_LEN - 1;                           \
            int t2 = d ? (T_LEN - 1 - s2) : s2;                                         \
            _Pragma("unroll")                                                           \
            for (int r = 0; r < 4; ++r)                                                 \
                XA[r] = xgp[(size_t)t2 * (BATCH * GDIM) + r * 256];                     \
        }                                                                               \
        bar_lds();                                                                      \
        hs = 1.f / 127.f;                                                               \
    }

    for (int s = 0; s < T_LEN; s += 2) {
        SCAN_SUBSTEP(s,     xe, 0, 1);
        SCAN_SUBSTEP(s + 1, xo, 1, 0);
    }
#undef SCAN_SUBSTEP
}

// ------------- feats[tb][k] = x[tb] . w_out[k] + b_out[k]  (one wave per tb) -------------
__global__ __launch_bounds__(64) void feats_k(const u16* __restrict__ X,      // [16384][512] bf16
                                              const float* __restrict__ Wout, // [7][512] f32
                                              const float* __restrict__ Bout, // [7] f32
                                              float* __restrict__ F) {        // [16384][8] f32
    int tb = blockIdx.x, lane = threadIdx.x;
    uint4 xv = ((const uint4*)(X + (size_t)tb * EDIM))[lane];   // 8 bf16 of x
    float xf[8];
    xf[0] = bflo(xv.x); xf[1] = bfhi(xv.x); xf[2] = bflo(xv.y); xf[3] = bfhi(xv.y);
    xf[4] = bflo(xv.z); xf[5] = bfhi(xv.z); xf[6] = bflo(xv.w); xf[7] = bfhi(xv.w);
    #pragma unroll
    for (int k = 0; k < KTAG; ++k) {
        const float4* wpo = (const float4*)(Wout + (size_t)k * EDIM) + lane * 2;
        float4 wa = wpo[0], wb = wpo[1];
        float p = 0.0f;
        p = fmaf(xf[0], wa.x, p); p = fmaf(xf[1], wa.y, p);
        p = fmaf(xf[2], wa.z, p); p = fmaf(xf[3], wa.w, p);
        p = fmaf(xf[4], wb.x, p); p = fmaf(xf[5], wb.y, p);
        p = fmaf(xf[6], wb.z, p); p = fmaf(xf[7], wb.w, p);
        #pragma unroll
        for (int off = 32; off > 0; off >>= 1) p += __shfl_xor(p, off, 64);
        if (lane == 0) F[tb * 8 + k] = p + Bout[k];
    }
}

// ------------- Viterbi: one wave, lane = batch; byte-packed backpointers -------------
// Backpointers stored TRANSPOSED: BPT[b][t] so the backtrace (256 dependent
// loads per lane) walks contiguous descending addresses (8 hops per 64-B line)
// instead of stride-512B scatter (one fresh L2 line per hop).
__global__ __launch_bounds__(64) void viterbi_k(const float* __restrict__ F,
                                                const float* __restrict__ Trans, // [7][7] next,prev
                                                u64* __restrict__ BPT,           // [64][256]
                                                float* __restrict__ OUT) {       // 16448 floats
    int b = threadIdx.x;
    float tr[KTAG][KTAG];
    #pragma unroll
    for (int n = 0; n < KTAG; ++n)
        #pragma unroll
        for (int p = 0; p < KTAG; ++p)
            tr[n][p] = Trans[n * KTAG + p];

    float v[KTAG];
    #pragma unroll
    for (int k = 0; k < KTAG; ++k) v[k] = (k == 5) ? 0.0f : NEGV;  // START=5

    float cf[KTAG], nf[KTAG];
    #pragma unroll
    for (int n = 0; n < KTAG; ++n) cf[n] = F[b * 8 + n];           // t=0

    for (int t = 0; t < T_LEN; ++t) {
        int tp = (t + 1 < T_LEN) ? t + 1 : t;
        #pragma unroll
        for (int n = 0; n < KTAG; ++n) nf[n] = F[((tp)*BATCH + b) * 8 + n];  // prefetch t+1

        u64 pk = 0;
        float nv[KTAG];
        #pragma unroll
        for (int n = 0; n < KTAG; ++n) {
            float best = v[0] + tr[n][0]; int bi = 0;
            #pragma unroll
            for (int p = 1; p < KTAG; ++p) {
                float s = v[p] + tr[n][p];
                if (s > best) { best = s; bi = p; }   // strict > == np.argmax first-max
            }
            pk |= ((u64)bi) << (8 * n);
            nv[n] = best + cf[n];
        }
        BPT[(b << 8) | t] = pk;
        #pragma unroll
        for (int n = 0; n < KTAG; ++n) { v[n] = nv[n]; cf[n] = nf[n]; }
    }
    float bs = v[0] + tr[6][0]; int tag = 0;          // STOP=6
    #pragma unroll
    for (int k = 1; k < KTAG; ++k) {
        float s = v[k] + tr[6][k];
        if (s > bs) { bs = s; tag = k; }
    }
    OUT[T_LEN * BATCH + b] = bs;                      // path_score [B]
    for (int t = T_LEN - 1; t >= 0; --t) {
        OUT[(size_t)b * T_LEN + t] = (float)tag;      // best_path [B][T]
        tag = (int)((BPT[(b << 8) | t] >> (8 * tag)) & 0xff);
    }
}

extern "C" void kernel_launch(void* const* d_in, const int* in_sizes, int n_in,
                              void* d_out, int out_size, void* d_ws, size_t ws_size,
                              hipStream_t stream) {
    const int*   sent  = (const int*)d_in[0];
    const float* emb   = (const float*)d_in[1];   // [50000][512]
    const float* w_ih  = (const float*)d_in[2];   // [2][2][1024][512]
    const float* w_hh  = (const float*)d_in[3];   // [2][2][1024][256]
    const float* b_ih  = (const float*)d_in[4];   // [2][2][1024]
    const float* b_hh  = (const float*)d_in[5];
    const float* w_out = (const float*)d_in[6];   // [7][512]
    const float* b_out = (const float*)d_in[7];   // [7]
    const float* trans = (const float*)d_in[8];   // [7][7]
    const float* h0    = (const float*)d_in[9];   // [4][64][256]
    const float* c0    = (const float*)d_in[10];
    float* out = (float*)d_out;

    char* ws = (char*)d_ws;
    u16*   xg    = (u16*)(ws);                       // 64 MB  [2][16384][1024] bf16
    u16*   x     = (u16*)(ws + 67108864);            // 16 MB  [16384][512] bf16
    u16*   wihB  = (u16*)(ws + 83886080);            // 4 MB   bf16 w_ih
    uint4* wq    = (uint4*)(ws + 88080384);          // 1 MB   int8 w_hh (packed)
    float* scl   = (float*)(ws + 89128960);          // 16 KB  scales
    float* feats = (float*)(ws + 89145344);          // 512 KB
    u64*   bpt   = (u64*)(ws + 89669632);            // 128 KB

    embed_k<<<16384, 64, 0, stream>>>(sent, emb, x);
    conv_wih<<<1024, 256, 0, stream>>>(w_ih, wihB);
    repack_whh_i8<<<16, 256, 0, stream>>>(w_hh, wq, scl);

    for (int l = 0; l < 2; ++l) {
        gemm_xg<<<dim3(128, 8, 2), 256, 0, stream>>>(
            x, wihB + (size_t)l * 2 * GDIM * EDIM,
            b_ih + (size_t)l * 2 * GDIM, b_hh + (size_t)l * 2 * GDIM, xg);
        // layer l's weights start at ld=2l; WQ ld-stride = 16384 uint4 -> offset l*32768
        lstm_scan_i8<<<128, 1024, 0, stream>>>(
            xg, wq + (size_t)l * 32768, scl + (size_t)l * 2048,
            h0 + (size_t)l * 2 * BATCH * HDIM, c0 + (size_t)l * 2 * BATCH * HDIM, x);
    }

    feats_k<<<16384, 64, 0, stream>>>(x, w_out, b_out, feats);
    viterbi_k<<<1, 64, 0, stream>>>(feats, trans, bpt, out);
}

// Round 7
// 1165.801 us; speedup vs baseline: 1.0265x; 1.0265x over previous
//
#include <hip/hip_runtime.h>
#include <stdint.h>

#define T_LEN 256
#define BATCH 64
#define EDIM  512
#define HDIM  256      // hidden per direction
#define GDIM  1024     // 4*HDIM
#define KTAG  7
#define NEGV  -10000.0f

using u16 = unsigned short;
using u32 = unsigned int;
using u64 = unsigned long long;

typedef short    bf16x8 __attribute__((ext_vector_type(8)));
typedef float    f32x4  __attribute__((ext_vector_type(4)));

__device__ __forceinline__ float bflo(u32 u) { return __uint_as_float(u << 16); }
__device__ __forceinline__ float bfhi(u32 u) { return __uint_as_float(u & 0xffff0000u); }
__device__ __forceinline__ float bf2f(u16 u) { return __uint_as_float(((u32)u) << 16); }
__device__ __forceinline__ u16 f2bf(float f) {
    u32 x = __float_as_uint(f);
    u32 r = x + 0x7fffu + ((x >> 16) & 1u);   // round-to-nearest-even
    return (u16)(r >> 16);
}
__device__ __forceinline__ u32 pack2(float a, float b) {
    return (u32)f2bf(a) | ((u32)f2bf(b) << 16);
}
// fast sigmoid / tanh (rel err ~1e-5, far below bf16 input noise)
__device__ __forceinline__ float fsig(float x)  { return __builtin_amdgcn_rcpf(1.f + __expf(-x)); }
__device__ __forceinline__ float ftanh(float x) { return 1.f - 2.f * __builtin_amdgcn_rcpf(1.f + __expf(2.f * x)); }

__device__ __forceinline__ int dot4i8(int a, int b, int c) {
#if __has_builtin(__builtin_amdgcn_sdot4)
    return __builtin_amdgcn_sdot4(a, b, c, false);     // v_dot4_i32_i8
#else
    c += (int)(signed char)(a & 0xff)         * (int)(signed char)(b & 0xff);
    c += (int)(signed char)((a >> 8) & 0xff)  * (int)(signed char)((b >> 8) & 0xff);
    c += (int)(signed char)((a >> 16) & 0xff) * (int)(signed char)((b >> 16) & 0xff);
    c += (int)(signed char)(a >> 24)          * (int)(signed char)(b >> 24);
    return c;
#endif
}

// light barrier: order LDS only; global loads/stores stay in flight (no vmcnt drain)
__device__ __forceinline__ void bar_lds() {
    asm volatile("s_waitcnt lgkmcnt(0)" ::: "memory");
    __builtin_amdgcn_s_barrier();
    asm volatile("" ::: "memory");
}

// async global->LDS, 16B per lane; LDS dest must be linear (base + lane*16)
__device__ __forceinline__ void gload_lds16(const void* g, void* l) {
    __builtin_amdgcn_global_load_lds((const __attribute__((address_space(1))) u32*)g,
                                     (__attribute__((address_space(3))) u32*)l, 16, 0, 0);
}

// ---------------- embedding gather+convert: x[tb][e] = bf16(emb[sent[tb]][e]) ----------------
__global__ __launch_bounds__(64) void embed_k(const int* __restrict__ sent,
                                              const float* __restrict__ emb,
                                              u16* __restrict__ X) {
    int tb = blockIdx.x;
    int tok = sent[tb];
    const float4* src = (const float4*)(emb + (size_t)tok * EDIM);
    float4 a = src[threadIdx.x * 2];
    float4 b = src[threadIdx.x * 2 + 1];
    uint4 o;
    o.x = pack2(a.x, a.y); o.y = pack2(a.z, a.w);
    o.z = pack2(b.x, b.y); o.w = pack2(b.z, b.w);
    ((uint4*)(X + (size_t)tb * EDIM))[threadIdx.x] = o;
}

// ---------------- convert w_ih f32 -> bf16, same layout [2][2][1024][512] ----------------
__global__ __launch_bounds__(256) void conv_wih(const float* __restrict__ W,
                                                u16* __restrict__ WB) {
    int g = blockIdx.x * 256 + threadIdx.x;          // 262144 groups of 8
    const float4* src = (const float4*)(W + (size_t)g * 8);
    float4 a = src[0], b = src[1];
    uint4 o;
    o.x = pack2(a.x, a.y); o.y = pack2(a.z, a.w);
    o.z = pack2(b.x, b.y); o.w = pack2(b.z, b.w);
    *(uint4*)(WB + (size_t)g * 8) = o;
}

// ---- quantize w_hh f32 [4][1024][256] -> int8 WQ[((ld*4+r)*16 + c8)*256 + j] uint4 + SCL ----
// chunk c8 (0..15) of row holds k = c8*16 .. c8*16+16.  SCL[ld*1024+row] = rowmax/127.
__global__ __launch_bounds__(256) void repack_whh_i8(const float* __restrict__ Whh,
                                                     uint4* __restrict__ WQ,
                                                     float* __restrict__ SCL) {
    int g  = blockIdx.x * 256 + threadIdx.x;    // 4096 rows
    int ld = g >> 10, row = g & 1023;
    const float* src = Whh + ((size_t)ld * GDIM + row) * HDIM;
    float m = 1e-30f;
    for (int k4 = 0; k4 < 64; ++k4) {
        float4 w = ((const float4*)src)[k4];
        m = fmaxf(m, fmaxf(fmaxf(fabsf(w.x), fabsf(w.y)), fmaxf(fabsf(w.z), fabsf(w.w))));
    }
    float inv = 127.f / m;
    SCL[ld * GDIM + row] = m / 127.f;
    int r = row >> 8, j = row & 255;
    for (int c8 = 0; c8 < 16; ++c8) {           // 16-byte chunks
        u32 dw[4];
        #pragma unroll
        for (int d4 = 0; d4 < 4; ++d4) {
            u32 p = 0;
            #pragma unroll
            for (int bb = 0; bb < 4; ++bb) {
                float w = src[c8 * 16 + d4 * 4 + bb];
                int q = (int)rintf(w * inv);
                q = q > 127 ? 127 : (q < -127 ? -127 : q);
                p |= ((u32)(q & 0xff)) << (8 * bb);
            }
            dw[d4] = p;
        }
        WQ[(size_t)(((ld * 4 + r) * 16 + c8) * 256 + j)] =
            (uint4){dw[0], dw[1], dw[2], dw[3]};
    }
}

// ------------- xg = x @ w_ih^T + b_ih + b_hh -------------
// 128x128 tile, BK=64, double-buffered gload_lds staging, 2-phase pipeline.
__global__ __launch_bounds__(256, 2) void gemm_xg(const u16* __restrict__ A,    // [16384][512] bf16
                                                  const u16* __restrict__ W,    // [2][1024][512] bf16
                                                  const float* __restrict__ Bih,// [2][1024] f32
                                                  const float* __restrict__ Bhh,
                                                  u16* __restrict__ XG) {       // [2][16384][1024] bf16
    const int d    = blockIdx.z;
    const int brow = blockIdx.x;               // 0..127 (M tiles)
    const int bcol = blockIdx.y;               // 0..7   (N tiles)
    const int tid  = threadIdx.x;
    const int lane = tid & 63;
    const int wv   = tid >> 6;                 // 4 waves: 2x2 of 64x64
    const int l15  = lane & 15;
    const int quad = lane >> 4;
    const int wr   = wv >> 1, wc = wv & 1;

    __shared__ u16 As[2][128 * 64];            // 2 x 16 KB, linear (gload_lds dest)
    __shared__ u16 Bs[2][128 * 64];            // 2 x 16 KB

    const u16* Wd = W + (size_t)d * GDIM * EDIM;
    const int srow = tid >> 3;                 // staging: 32 rows / issue
    const int scol = (tid & 7) * 8;            // u16 units (16 B per lane)
    const u16* ga = A  + (size_t)(brow * 128 + srow) * EDIM + scol;
    const u16* gb = Wd + (size_t)(bcol * 128 + srow) * EDIM + scol;
    const int loff = srow * 64 + scol;

    f32x4 acc[4][4];
    #pragma unroll
    for (int mt = 0; mt < 4; ++mt)
        #pragma unroll
        for (int nt = 0; nt < 4; ++nt)
            acc[mt][nt] = (f32x4){0.f, 0.f, 0.f, 0.f};

    // prologue: stage tile 0
    #pragma unroll
    for (int it = 0; it < 4; ++it) {
        gload_lds16(ga + (size_t)(it * 32) * EDIM, &As[0][loff + it * 32 * 64]);
        gload_lds16(gb + (size_t)(it * 32) * EDIM, &Bs[0][loff + it * 32 * 64]);
    }
    __syncthreads();

    int cur = 0;
    for (int t = 0; t < 8; ++t) {
        if (t < 7) {                           // issue next tile into other buffer
            int k0 = (t + 1) * 64;
            #pragma unroll
            for (int it = 0; it < 4; ++it) {
                gload_lds16(ga + (size_t)(it * 32) * EDIM + k0, &As[cur ^ 1][loff + it * 32 * 64]);
                gload_lds16(gb + (size_t)(it * 32) * EDIM + k0, &Bs[cur ^ 1][loff + it * 32 * 64]);
            }
        }
        const u16* Ab = As[cur];
        const u16* Bb = Bs[cur];
        #pragma unroll
        for (int ks = 0; ks < 2; ++ks) {
            bf16x8 av[4], bv[4];
            #pragma unroll
            for (int mt = 0; mt < 4; ++mt)
                av[mt] = *(const bf16x8*)(Ab + (wr * 64 + mt * 16 + l15) * 64 + ks * 32 + quad * 8);
            #pragma unroll
            for (int nt = 0; nt < 4; ++nt)
                bv[nt] = *(const bf16x8*)(Bb + (wc * 64 + nt * 16 + l15) * 64 + ks * 32 + quad * 8);
            #pragma unroll
            for (int mt = 0; mt < 4; ++mt)
                #pragma unroll
                for (int nt = 0; nt < 4; ++nt)
                    acc[mt][nt] = __builtin_amdgcn_mfma_f32_16x16x32_bf16(av[mt], bv[nt], acc[mt][nt], 0, 0, 0);
        }
        __syncthreads();                       // drains vmcnt: next tile ready, reads done
        cur ^= 1;
    }

    u16* xgd = XG + (size_t)d * ((size_t)16384 * GDIM);
    #pragma unroll
    for (int nt = 0; nt < 4; ++nt) {
        int col = bcol * 128 + wc * 64 + nt * 16 + l15;   // C/D: col=lane&15, row=quad*4+reg
        float bias = Bih[d * GDIM + col] + Bhh[d * GDIM + col];
        #pragma unroll
        for (int mt = 0; mt < 4; ++mt) {
            int row0 = brow * 128 + wr * 64 + mt * 16 + quad * 4;
            #pragma unroll
            for (int r = 0; r < 4; ++r)
                xgd[(size_t)(row0 + r) * GDIM + col] = f2bf(acc[mt][nt][r] + bias);
        }
    }
}

// ------------- recurrent scan: 512 threads, int8 weights AGPR-resident -------------
// 128 blocks = (d,b); 512 threads: j = tid&255, half = tid>>8 (K-half).
// R6 post-mortem: 1024-thr blocks hard-cap at 128 TOTAL regs/wave (unified
// VGPR+AGPR file, 4 waves/EU); R5 launched at 60V+64A=124, R6's +16 temps
// exceeded the cap -> unlaunchable. Fix: 512-thr blocks (2 waves/EU min) cap
// at 256 regs/wave. Each thread holds its 128 weight dwords (4 gate rows x
// K-half) in AGPRs: written once via v_accvgpr_write, read back in 8-wide
// volatile asm blocks (reads pipeline back-to-back; R5's per-use {read;dot}
// pairs serialized on the AGPR->VALU hazard). ~128A + ~85V = ~215 <= 256.
// Integer accumulation order per chain unchanged -> bit-identical output.
#define LDW(r, c, n0, n1, n2, n3) do {                                              \
    uint4 t_ = WQ[(size_t)(((d * 4 + (r)) * 16 + half * 8 + (c)) * 256 + j)];       \
    asm volatile("v_accvgpr_write_b32 %0, %1" : "=a"(Wa##n0) : "v"(t_.x));          \
    asm volatile("v_accvgpr_write_b32 %0, %1" : "=a"(Wa##n1) : "v"(t_.y));          \
    asm volatile("v_accvgpr_write_b32 %0, %1" : "=a"(Wa##n2) : "v"(t_.z));          \
    asm volatile("v_accvgpr_write_b32 %0, %1" : "=a"(Wa##n3) : "v"(t_.w));          \
  } while (0)

// 8 back-to-back AGPR->VGPR reads in ONE asm block (pipelined, no per-read fence)
#define RD8(T0,T1,T2,T3,T4,T5,T6,T7, A0,A1,A2,A3,A4,A5,A6,A7)                       \
    asm volatile("v_accvgpr_read_b32 %0, %8\n\t"                                    \
                 "v_accvgpr_read_b32 %1, %9\n\t"                                    \
                 "v_accvgpr_read_b32 %2, %10\n\t"                                   \
                 "v_accvgpr_read_b32 %3, %11\n\t"                                   \
                 "v_accvgpr_read_b32 %4, %12\n\t"                                   \
                 "v_accvgpr_read_b32 %5, %13\n\t"                                   \
                 "v_accvgpr_read_b32 %6, %14\n\t"                                   \
                 "v_accvgpr_read_b32 %7, %15"                                       \
                 : "=v"(T0), "=v"(T1), "=v"(T2), "=v"(T3),                          \
                   "=v"(T4), "=v"(T5), "=v"(T6), "=v"(T7)                           \
                 : "a"(A0), "a"(A1), "a"(A2), "a"(A3),                              \
                   "a"(A4), "a"(A5), "a"(A6), "a"(A7))

// one 16-byte K-chunk: rows 0,1 read+dot, then rows 2,3 read+dot
#define CHUNK(HV, P0,P1,P2,P3, Q0,Q1,Q2,Q3, R0,R1,R2,R3, S0,S1,S2,S3)               \
    { u32 t0,t1,t2,t3,t4,t5,t6,t7;                                                  \
      RD8(t0,t1,t2,t3,t4,t5,t6,t7,                                                  \
          Wa##P0,Wa##P1,Wa##P2,Wa##P3, Wa##Q0,Wa##Q1,Wa##Q2,Wa##Q3);                \
      a0 = dot4i8((int)t0, (int)(HV).x, a0); a1 = dot4i8((int)t4, (int)(HV).x, a1); \
      a0 = dot4i8((int)t1, (int)(HV).y, a0); a1 = dot4i8((int)t5, (int)(HV).y, a1); \
      a0 = dot4i8((int)t2, (int)(HV).z, a0); a1 = dot4i8((int)t6, (int)(HV).z, a1); \
      a0 = dot4i8((int)t3, (int)(HV).w, a0); a1 = dot4i8((int)t7, (int)(HV).w, a1); \
      RD8(t0,t1,t2,t3,t4,t5,t6,t7,                                                  \
          Wa##R0,Wa##R1,Wa##R2,Wa##R3, Wa##S0,Wa##S1,Wa##S2,Wa##S3);                \
      a2 = dot4i8((int)t0, (int)(HV).x, a2); a3 = dot4i8((int)t4, (int)(HV).x, a3); \
      a2 = dot4i8((int)t1, (int)(HV).y, a2); a3 = dot4i8((int)t5, (int)(HV).y, a3); \
      a2 = dot4i8((int)t2, (int)(HV).z, a2); a3 = dot4i8((int)t6, (int)(HV).z, a3); \
      a2 = dot4i8((int)t3, (int)(HV).w, a2); a3 = dot4i8((int)t7, (int)(HV).w, a3); }

__global__ __launch_bounds__(512) void lstm_scan_i8(
        const u16* __restrict__ XG,        // [2][16384][1024] bf16 (this layer)
        const uint4* __restrict__ WQ,      // this layer's int8 slice
        const float* __restrict__ SCL,     // [2][1024] weight LSB
        const float* __restrict__ H0,      // [2][64][256] f32
        const float* __restrict__ C0,
        u16* __restrict__ XOUT) {          // [16384][512] bf16
    const int b    = blockIdx.x & 63;
    const int d    = blockIdx.x >> 6;
    const int tid  = threadIdx.x;
    const int j    = tid & 255;
    const int half = tid >> 8;             // K-half 0..1 (wave-uniform)

    __shared__ uint4 hq[2][16];            // double-buffered int8 h (2 x 256 B)
    __shared__ float ps[4][256];           // half1 integer partials (exact f32)

    // ---- 128 weight dwords, AGPR-resident for the whole scan ----
    u32 Wa0,Wa1,Wa2,Wa3,Wa4,Wa5,Wa6,Wa7,Wa8,Wa9,Wa10,Wa11,Wa12,Wa13,Wa14,Wa15;
    u32 Wa16,Wa17,Wa18,Wa19,Wa20,Wa21,Wa22,Wa23,Wa24,Wa25,Wa26,Wa27,Wa28,Wa29,Wa30,Wa31;
    u32 Wa32,Wa33,Wa34,Wa35,Wa36,Wa37,Wa38,Wa39,Wa40,Wa41,Wa42,Wa43,Wa44,Wa45,Wa46,Wa47;
    u32 Wa48,Wa49,Wa50,Wa51,Wa52,Wa53,Wa54,Wa55,Wa56,Wa57,Wa58,Wa59,Wa60,Wa61,Wa62,Wa63;
    u32 Wa64,Wa65,Wa66,Wa67,Wa68,Wa69,Wa70,Wa71,Wa72,Wa73,Wa74,Wa75,Wa76,Wa77,Wa78,Wa79;
    u32 Wa80,Wa81,Wa82,Wa83,Wa84,Wa85,Wa86,Wa87,Wa88,Wa89,Wa90,Wa91,Wa92,Wa93,Wa94,Wa95;
    u32 Wa96,Wa97,Wa98,Wa99,Wa100,Wa101,Wa102,Wa103,Wa104,Wa105,Wa106,Wa107;
    u32 Wa108,Wa109,Wa110,Wa111,Wa112,Wa113,Wa114,Wa115,Wa116,Wa117,Wa118,Wa119;
    u32 Wa120,Wa121,Wa122,Wa123,Wa124,Wa125,Wa126,Wa127;

    LDW(0,0,  0,  1,  2,  3); LDW(0,1,  4,  5,  6,  7);
    LDW(0,2,  8,  9, 10, 11); LDW(0,3, 12, 13, 14, 15);
    LDW(0,4, 16, 17, 18, 19); LDW(0,5, 20, 21, 22, 23);
    LDW(0,6, 24, 25, 26, 27); LDW(0,7, 28, 29, 30, 31);
    LDW(1,0, 32, 33, 34, 35); LDW(1,1, 36, 37, 38, 39);
    LDW(1,2, 40, 41, 42, 43); LDW(1,3, 44, 45, 46, 47);
    LDW(1,4, 48, 49, 50, 51); LDW(1,5, 52, 53, 54, 55);
    LDW(1,6, 56, 57, 58, 59); LDW(1,7, 60, 61, 62, 63);
    LDW(2,0, 64, 65, 66, 67); LDW(2,1, 68, 69, 70, 71);
    LDW(2,2, 72, 73, 74, 75); LDW(2,3, 76, 77, 78, 79);
    LDW(2,4, 80, 81, 82, 83); LDW(2,5, 84, 85, 86, 87);
    LDW(2,6, 88, 89, 90, 91); LDW(2,7, 92, 93, 94, 95);
    LDW(3,0, 96, 97, 98, 99); LDW(3,1,100,101,102,103);
    LDW(3,2,104,105,106,107); LDW(3,3,108,109,110,111);
    LDW(3,4,112,113,114,115); LDW(3,5,116,117,118,119);
    LDW(3,6,120,121,122,123); LDW(3,7,124,125,126,127);

    float scl0 = 0.f, scl1 = 0.f, scl2 = 0.f, scl3 = 0.f, cst = 0.f;
    if (half == 0) {
        scl0 = SCL[d * GDIM + 0 * 256 + j];
        scl1 = SCL[d * GDIM + 1 * 256 + j];
        scl2 = SCL[d * GDIM + 2 * 256 + j];
        scl3 = SCL[d * GDIM + 3 * 256 + j];
        float h0v = H0[((size_t)d * BATCH + b) * HDIM + j];
        cst       = C0[((size_t)d * BATCH + b) * HDIM + j];
        int qz = (int)rintf(h0v * 31.75f);                 // scale 127/4 (|h0| can exceed 1)
        qz = qz > 127 ? 127 : (qz < -127 ? -127 : qz);
        ((signed char*)hq)[j] = (signed char)qz;           // buffer 0
    }
    __syncthreads();

    const u16* xgp = XG + (size_t)d * ((size_t)16384 * GDIM) + (size_t)b * GDIM + j;
    // even/odd register pipeline: xe used at even steps, xo at odd; reload 2 steps ahead
    u16 xe[4], xo[4];
    if (half == 0) {
        int t0 = d ? T_LEN - 1 : 0;
        int t1 = d ? T_LEN - 2 : 1;
        #pragma unroll
        for (int r = 0; r < 4; ++r) xe[r] = xgp[(size_t)t0 * (BATCH * GDIM) + r * 256];
        #pragma unroll
        for (int r = 0; r < 4; ++r) xo[r] = xgp[(size_t)t1 * (BATCH * GDIM) + r * 256];
    }

    float hs = 4.f / 127.f;                // h LSB for step 0 input h; 1/127 afterwards

#define SCAN_SUBSTEP(S, XA, RB, WB)                                                     \
    {                                                                                   \
        const int t_ = d ? (T_LEN - 1 - (S)) : (S);                                     \
        const uint4* hb = (const uint4*)hq + (RB) * 16 + half * 8;                      \
        uint4 hv[8];                                                                    \
        _Pragma("unroll")                                                               \
        for (int c = 0; c < 8; ++c) hv[c] = hb[c];          /* wave-uniform: broadcast */\
        int a0 = 0, a1 = 0, a2 = 0, a3 = 0;                                             \
        CHUNK(hv[0],  0,  1,  2,  3,  32, 33, 34, 35,  64, 65, 66, 67,  96, 97, 98, 99);\
        CHUNK(hv[1],  4,  5,  6,  7,  36, 37, 38, 39,  68, 69, 70, 71, 100,101,102,103);\
        CHUNK(hv[2],  8,  9, 10, 11,  40, 41, 42, 43,  72, 73, 74, 75, 104,105,106,107);\
        CHUNK(hv[3], 12, 13, 14, 15,  44, 45, 46, 47,  76, 77, 78, 79, 108,109,110,111);\
        CHUNK(hv[4], 16, 17, 18, 19,  48, 49, 50, 51,  80, 81, 82, 83, 112,113,114,115);\
        CHUNK(hv[5], 20, 21, 22, 23,  52, 53, 54, 55,  84, 85, 86, 87, 116,117,118,119);\
        CHUNK(hv[6], 24, 25, 26, 27,  56, 57, 58, 59,  88, 89, 90, 91, 120,121,122,123);\
        CHUNK(hv[7], 28, 29, 30, 31,  60, 61, 62, 63,  92, 93, 94, 95, 124,125,126,127);\
        if (half == 1) {                                   /* |acc| < 2^22: f32-exact */\
            ps[0][j] = (float)a0; ps[1][j] = (float)a1;                                 \
            ps[2][j] = (float)a2; ps[3][j] = (float)a3;                                 \
        }                                                                               \
        bar_lds();                                                                      \
        if (half == 0) {                                                                \
            float g0 = bf2f(XA[0]) + ((float)a0 + ps[0][j]) * (scl0 * hs);              \
            float g1 = bf2f(XA[1]) + ((float)a1 + ps[1][j]) * (scl1 * hs);              \
            float g2 = bf2f(XA[2]) + ((float)a2 + ps[2][j]) * (scl2 * hs);              \
            float g3 = bf2f(XA[3]) + ((float)a3 + ps[3][j]) * (scl3 * hs);              \
            float iv = fsig(g0), fv = fsig(g1), gv = ftanh(g2), ov = fsig(g3);          \
            cst = fv * cst + iv * gv;                                                   \
            float h = ov * ftanh(cst);                                                  \
            XOUT[((size_t)t_ * BATCH + b) * EDIM + d * HDIM + j] = f2bf(h);             \
            int qz = (int)rintf(h * 127.f);                /* |h|<1: scale 1/127 */     \
            qz = qz > 127 ? 127 : (qz < -127 ? -127 : qz);                              \
            ((signed char*)hq)[(WB) * 256 + j] = (signed char)qz;                       \
            int s2 = ((S) + 2 < T_LEN) ? (S) + 2 : T_LEN - 1;                           \
            int t2 = d ? (T_LEN - 1 - s2) : s2;                                         \
            _Pragma("unroll")                                                           \
            for (int r = 0; r < 4; ++r)                                                 \
                XA[r] = xgp[(size_t)t2 * (BATCH * GDIM) + r * 256];                     \
        }                                                                               \
        bar_lds();                                                                      \
        hs = 1.f / 127.f;                                                               \
    }

    for (int s = 0; s < T_LEN; s += 2) {
        SCAN_SUBSTEP(s,     xe, 0, 1);
        SCAN_SUBSTEP(s + 1, xo, 1, 0);
    }
#undef SCAN_SUBSTEP
}

// ------------- feats[tb][k] = x[tb] . w_out[k] + b_out[k]  (one wave per tb) -------------
__global__ __launch_bounds__(64) void feats_k(const u16* __restrict__ X,      // [16384][512] bf16
                                              const float* __restrict__ Wout, // [7][512] f32
                                              const float* __restrict__ Bout, // [7] f32
                                              float* __restrict__ F) {        // [16384][8] f32
    int tb = blockIdx.x, lane = threadIdx.x;
    uint4 xv = ((const uint4*)(X + (size_t)tb * EDIM))[lane];   // 8 bf16 of x
    float xf[8];
    xf[0] = bflo(xv.x); xf[1] = bfhi(xv.x); xf[2] = bflo(xv.y); xf[3] = bfhi(xv.y);
    xf[4] = bflo(xv.z); xf[5] = bfhi(xv.z); xf[6] = bflo(xv.w); xf[7] = bfhi(xv.w);
    #pragma unroll
    for (int k = 0; k < KTAG; ++k) {
        const float4* wpo = (const float4*)(Wout + (size_t)k * EDIM) + lane * 2;
        float4 wa = wpo[0], wb = wpo[1];
        float p = 0.0f;
        p = fmaf(xf[0], wa.x, p); p = fmaf(xf[1], wa.y, p);
        p = fmaf(xf[2], wa.z, p); p = fmaf(xf[3], wa.w, p);
        p = fmaf(xf[4], wb.x, p); p = fmaf(xf[5], wb.y, p);
        p = fmaf(xf[6], wb.z, p); p = fmaf(xf[7], wb.w, p);
        #pragma unroll
        for (int off = 32; off > 0; off >>= 1) p += __shfl_xor(p, off, 64);
        if (lane == 0) F[tb * 8 + k] = p + Bout[k];
    }
}

// ------------- Viterbi: one wave, lane = batch; byte-packed backpointers -------------
// Backpointers stored TRANSPOSED: BPT[b][t] so the backtrace (256 dependent
// loads per lane) walks contiguous descending addresses (8 hops per 64-B line)
// instead of stride-512B scatter (one fresh L2 line per hop).
__global__ __launch_bounds__(64) void viterbi_k(const float* __restrict__ F,
                                                const float* __restrict__ Trans, // [7][7] next,prev
                                                u64* __restrict__ BPT,           // [64][256]
                                                float* __restrict__ OUT) {       // 16448 floats
    int b = threadIdx.x;
    float tr[KTAG][KTAG];
    #pragma unroll
    for (int n = 0; n < KTAG; ++n)
        #pragma unroll
        for (int p = 0; p < KTAG; ++p)
            tr[n][p] = Trans[n * KTAG + p];

    float v[KTAG];
    #pragma unroll
    for (int k = 0; k < KTAG; ++k) v[k] = (k == 5) ? 0.0f : NEGV;  // START=5

    float cf[KTAG], nf[KTAG];
    #pragma unroll
    for (int n = 0; n < KTAG; ++n) cf[n] = F[b * 8 + n];           // t=0

    for (int t = 0; t < T_LEN; ++t) {
        int tp = (t + 1 < T_LEN) ? t + 1 : t;
        #pragma unroll
        for (int n = 0; n < KTAG; ++n) nf[n] = F[((tp)*BATCH + b) * 8 + n];  // prefetch t+1

        u64 pk = 0;
        float nv[KTAG];
        #pragma unroll
        for (int n = 0; n < KTAG; ++n) {
            float best = v[0] + tr[n][0]; int bi = 0;
            #pragma unroll
            for (int p = 1; p < KTAG; ++p) {
                float s = v[p] + tr[n][p];
                if (s > best) { best = s; bi = p; }   // strict > == np.argmax first-max
            }
            pk |= ((u64)bi) << (8 * n);
            nv[n] = best + cf[n];
        }
        BPT[(b << 8) | t] = pk;
        #pragma unroll
        for (int n = 0; n < KTAG; ++n) { v[n] = nv[n]; cf[n] = nf[n]; }
    }
    float bs = v[0] + tr[6][0]; int tag = 0;          // STOP=6
    #pragma unroll
    for (int k = 1; k < KTAG; ++k) {
        float s = v[k] + tr[6][k];
        if (s > bs) { bs = s; tag = k; }
    }
    OUT[T_LEN * BATCH + b] = bs;                      // path_score [B]
    for (int t = T_LEN - 1; t >= 0; --t) {
        OUT[(size_t)b * T_LEN + t] = (float)tag;      // best_path [B][T]
        tag = (int)((BPT[(b << 8) | t] >> (8 * tag)) & 0xff);
    }
}

extern "C" void kernel_launch(void* const* d_in, const int* in_sizes, int n_in,
                              void* d_out, int out_size, void* d_ws, size_t ws_size,
                              hipStream_t stream) {
    const int*   sent  = (const int*)d_in[0];
    const float* emb   = (const float*)d_in[1];   // [50000][512]
    const float* w_ih  = (const float*)d_in[2];   // [2][2][1024][512]
    const float* w_hh  = (const float*)d_in[3];   // [2][2][1024][256]
    const float* b_ih  = (const float*)d_in[4];   // [2][2][1024]
    const float* b_hh  = (const float*)d_in[5];
    const float* w_out = (const float*)d_in[6];   // [7][512]
    const float* b_out = (const float*)d_in[7];   // [7]
    const float* trans = (const float*)d_in[8];   // [7][7]
    const float* h0    = (const float*)d_in[9];   // [4][64][256]
    const float* c0    = (const float*)d_in[10];
    float* out = (float*)d_out;

    char* ws = (char*)d_ws;
    u16*   xg    = (u16*)(ws);                       // 64 MB  [2][16384][1024] bf16
    u16*   x     = (u16*)(ws + 67108864);            // 16 MB  [16384][512] bf16
    u16*   wihB  = (u16*)(ws + 83886080);            // 4 MB   bf16 w_ih
    uint4* wq    = (uint4*)(ws + 88080384);          // 1 MB   int8 w_hh (packed)
    float* scl   = (float*)(ws + 89128960);          // 16 KB  scales
    float* feats = (float*)(ws + 89145344);          // 512 KB
    u64*   bpt   = (u64*)(ws + 89669632);            // 128 KB

    embed_k<<<16384, 64, 0, stream>>>(sent, emb, x);
    conv_wih<<<1024, 256, 0, stream>>>(w_ih, wihB);
    repack_whh_i8<<<16, 256, 0, stream>>>(w_hh, wq, scl);

    for (int l = 0; l < 2; ++l) {
        gemm_xg<<<dim3(128, 8, 2), 256, 0, stream>>>(
            x, wihB + (size_t)l * 2 * GDIM * EDIM,
            b_ih + (size_t)l * 2 * GDIM, b_hh + (size_t)l * 2 * GDIM, xg);
        // layer l's weights start at ld=2l; WQ ld-stride = 16384 uint4 -> offset l*32768
        lstm_scan_i8<<<128, 512, 0, stream>>>(
            xg, wq + (size_t)l * 32768, scl + (size_t)l * 2048,
            h0 + (size_t)l * 2 * BATCH * HDIM, c0 + (size_t)l * 2 * BATCH * HDIM, x);
    }

    feats_k<<<16384, 64, 0, stream>>>(x, w_out, b_out, feats);
    viterbi_k<<<1, 64, 0, stream>>>(feats, trans, bpt, out);
}

// Round 8
// 897.403 us; speedup vs baseline: 1.3335x; 1.2991x over previous
//
#include <hip/hip_runtime.h>
#include <stdint.h>

#define T_LEN 256
#define BATCH 64
#define EDIM  512
#define HDIM  256      // hidden per direction
#define GDIM  1024     // 4*HDIM
#define KTAG  7
#define NEGV  -10000.0f

using u16 = unsigned short;
using u32 = unsigned int;
using u64 = unsigned long long;

typedef short    bf16x8 __attribute__((ext_vector_type(8)));
typedef float    f32x4  __attribute__((ext_vector_type(4)));

__device__ __forceinline__ float bflo(u32 u) { return __uint_as_float(u << 16); }
__device__ __forceinline__ float bfhi(u32 u) { return __uint_as_float(u & 0xffff0000u); }
__device__ __forceinline__ float bf2f(u16 u) { return __uint_as_float(((u32)u) << 16); }
__device__ __forceinline__ u16 f2bf(float f) {
    u32 x = __float_as_uint(f);
    u32 r = x + 0x7fffu + ((x >> 16) & 1u);   // round-to-nearest-even
    return (u16)(r >> 16);
}
__device__ __forceinline__ u32 pack2(float a, float b) {
    return (u32)f2bf(a) | ((u32)f2bf(b) << 16);
}
// fast sigmoid / tanh (rel err ~1e-5, far below bf16 input noise)
__device__ __forceinline__ float fsig(float x)  { return __builtin_amdgcn_rcpf(1.f + __expf(-x)); }
__device__ __forceinline__ float ftanh(float x) { return 1.f - 2.f * __builtin_amdgcn_rcpf(1.f + __expf(2.f * x)); }

__device__ __forceinline__ int dot4i8(int a, int b, int c) {
#if __has_builtin(__builtin_amdgcn_sdot4)
    return __builtin_amdgcn_sdot4(a, b, c, false);     // v_dot4_i32_i8
#else
    c += (int)(signed char)(a & 0xff)         * (int)(signed char)(b & 0xff);
    c += (int)(signed char)((a >> 8) & 0xff)  * (int)(signed char)((b >> 8) & 0xff);
    c += (int)(signed char)((a >> 16) & 0xff) * (int)(signed char)((b >> 16) & 0xff);
    c += (int)(signed char)(a >> 24)          * (int)(signed char)(b >> 24);
    return c;
#endif
}

// light barrier: order LDS only; global loads/stores stay in flight (no vmcnt drain)
__device__ __forceinline__ void bar_lds() {
    asm volatile("s_waitcnt lgkmcnt(0)" ::: "memory");
    __builtin_amdgcn_s_barrier();
    asm volatile("" ::: "memory");
}

// async global->LDS, 16B per lane; LDS dest must be linear (base + lane*16)
__device__ __forceinline__ void gload_lds16(const void* g, void* l) {
    __builtin_amdgcn_global_load_lds((const __attribute__((address_space(1))) u32*)g,
                                     (__attribute__((address_space(3))) u32*)l, 16, 0, 0);
}

// ---------------- embedding gather+convert: x[tb][e] = bf16(emb[sent[tb]][e]) ----------------
__global__ __launch_bounds__(64) void embed_k(const int* __restrict__ sent,
                                              const float* __restrict__ emb,
                                              u16* __restrict__ X) {
    int tb = blockIdx.x;
    int tok = sent[tb];
    const float4* src = (const float4*)(emb + (size_t)tok * EDIM);
    float4 a = src[threadIdx.x * 2];
    float4 b = src[threadIdx.x * 2 + 1];
    uint4 o;
    o.x = pack2(a.x, a.y); o.y = pack2(a.z, a.w);
    o.z = pack2(b.x, b.y); o.w = pack2(b.z, b.w);
    ((uint4*)(X + (size_t)tb * EDIM))[threadIdx.x] = o;
}

// ---------------- convert w_ih f32 -> bf16, same layout [2][2][1024][512] ----------------
__global__ __launch_bounds__(256) void conv_wih(const float* __restrict__ W,
                                                u16* __restrict__ WB) {
    int g = blockIdx.x * 256 + threadIdx.x;          // 262144 groups of 8
    const float4* src = (const float4*)(W + (size_t)g * 8);
    float4 a = src[0], b = src[1];
    uint4 o;
    o.x = pack2(a.x, a.y); o.y = pack2(a.z, a.w);
    o.z = pack2(b.x, b.y); o.w = pack2(b.z, b.w);
    *(uint4*)(WB + (size_t)g * 8) = o;
}

// ---- quantize w_hh f32 [4][1024][256] -> int8 WQ[((ld*4+r)*16 + c8)*256 + j] uint4 + SCL ----
// chunk c8 (0..15) of row holds k = c8*16 .. c8*16+16.  SCL[ld*1024+row] = rowmax/127.
__global__ __launch_bounds__(256) void repack_whh_i8(const float* __restrict__ Whh,
                                                     uint4* __restrict__ WQ,
                                                     float* __restrict__ SCL) {
    int g  = blockIdx.x * 256 + threadIdx.x;    // 4096 rows
    int ld = g >> 10, row = g & 1023;
    const float* src = Whh + ((size_t)ld * GDIM + row) * HDIM;
    float m = 1e-30f;
    for (int k4 = 0; k4 < 64; ++k4) {
        float4 w = ((const float4*)src)[k4];
        m = fmaxf(m, fmaxf(fmaxf(fabsf(w.x), fabsf(w.y)), fmaxf(fabsf(w.z), fabsf(w.w))));
    }
    float inv = 127.f / m;
    SCL[ld * GDIM + row] = m / 127.f;
    int r = row >> 8, j = row & 255;
    for (int c8 = 0; c8 < 16; ++c8) {           // 16-byte chunks
        u32 dw[4];
        #pragma unroll
        for (int d4 = 0; d4 < 4; ++d4) {
            u32 p = 0;
            #pragma unroll
            for (int bb = 0; bb < 4; ++bb) {
                float w = src[c8 * 16 + d4 * 4 + bb];
                int q = (int)rintf(w * inv);
                q = q > 127 ? 127 : (q < -127 ? -127 : q);
                p |= ((u32)(q & 0xff)) << (8 * bb);
            }
            dw[d4] = p;
        }
        WQ[(size_t)(((ld * 4 + r) * 16 + c8) * 256 + j)] =
            (uint4){dw[0], dw[1], dw[2], dw[3]};
    }
}

// ------------- xg = x @ w_ih^T + b_ih + b_hh -------------
// 128x128 tile, BK=64, double-buffered gload_lds staging, COUNTED-vmcnt pipeline
// (T4 recipe): each wave issues 8 gload_lds insts per K-tile; at each tile we
// wait vmcnt(8) (tile-t loads done, tile-t+1's 8 stay IN FLIGHT across the raw
// s_barrier) instead of __syncthreads' full vmcnt(0) drain. Loads ride one full
// iteration ahead -> the ~900-cyc latency that used to be exposed per tile is
// hidden under the previous tile's MFMA. MFMA order unchanged -> bit-identical.
__global__ __launch_bounds__(256, 2) void gemm_xg(const u16* __restrict__ A,    // [16384][512] bf16
                                                  const u16* __restrict__ W,    // [2][1024][512] bf16
                                                  const float* __restrict__ Bih,// [2][1024] f32
                                                  const float* __restrict__ Bhh,
                                                  u16* __restrict__ XG) {       // [2][16384][1024] bf16
    const int d    = blockIdx.z;
    const int brow = blockIdx.x;               // 0..127 (M tiles)
    const int bcol = blockIdx.y;               // 0..7   (N tiles)
    const int tid  = threadIdx.x;
    const int lane = tid & 63;
    const int wv   = tid >> 6;                 // 4 waves: 2x2 of 64x64
    const int l15  = lane & 15;
    const int quad = lane >> 4;
    const int wr   = wv >> 1, wc = wv & 1;

    __shared__ u16 As[2][128 * 64];            // 2 x 16 KB, linear (gload_lds dest)
    __shared__ u16 Bs[2][128 * 64];            // 2 x 16 KB

    const u16* Wd = W + (size_t)d * GDIM * EDIM;
    const int srow = tid >> 3;                 // staging: 32 rows / issue
    const int scol = (tid & 7) * 8;            // u16 units (16 B per lane)
    const u16* ga = A  + (size_t)(brow * 128 + srow) * EDIM + scol;
    const u16* gb = Wd + (size_t)(bcol * 128 + srow) * EDIM + scol;
    const int loff = srow * 64 + scol;

#define STAGE(buf, kt)                                                              \
    { int k0_ = (kt) * 64;                                                          \
      _Pragma("unroll")                                                             \
      for (int it = 0; it < 4; ++it) {                                              \
          gload_lds16(ga + (size_t)(it * 32) * EDIM + k0_, &As[buf][loff + it * 32 * 64]); \
          gload_lds16(gb + (size_t)(it * 32) * EDIM + k0_, &Bs[buf][loff + it * 32 * 64]); \
      } }

    f32x4 acc[4][4];
    #pragma unroll
    for (int mt = 0; mt < 4; ++mt)
        #pragma unroll
        for (int nt = 0; nt < 4; ++nt)
            acc[mt][nt] = (f32x4){0.f, 0.f, 0.f, 0.f};

    // prologue: tiles 0 and 1 in flight (16 outstanding vmem insts per wave)
    STAGE(0, 0);
    STAGE(1, 1);

    for (int t = 0; t < 8; ++t) {
        // wait only for tile t's 8 loads; tile t+1's 8 stay in flight
        if (t < 7) { asm volatile("s_waitcnt vmcnt(8)" ::: "memory"); }
        else       { asm volatile("s_waitcnt vmcnt(0)" ::: "memory"); }
        __builtin_amdgcn_s_barrier();

        const u16* Ab = As[t & 1];
        const u16* Bb = Bs[t & 1];
        #pragma unroll
        for (int ks = 0; ks < 2; ++ks) {
            bf16x8 av[4], bv[4];
            #pragma unroll
            for (int mt = 0; mt < 4; ++mt)
                av[mt] = *(const bf16x8*)(Ab + (wr * 64 + mt * 16 + l15) * 64 + ks * 32 + quad * 8);
            #pragma unroll
            for (int nt = 0; nt < 4; ++nt)
                bv[nt] = *(const bf16x8*)(Bb + (wc * 64 + nt * 16 + l15) * 64 + ks * 32 + quad * 8);
            #pragma unroll
            for (int mt = 0; mt < 4; ++mt)
                #pragma unroll
                for (int nt = 0; nt < 4; ++nt)
                    acc[mt][nt] = __builtin_amdgcn_mfma_f32_16x16x32_bf16(av[mt], bv[nt], acc[mt][nt], 0, 0, 0);
        }

        // all ds_reads of this buffer complete, then barrier, then overwrite it
        asm volatile("s_waitcnt lgkmcnt(0)" ::: "memory");
        __builtin_amdgcn_s_barrier();
        if (t < 6) STAGE(t & 1, t + 2);
    }
#undef STAGE

    u16* xgd = XG + (size_t)d * ((size_t)16384 * GDIM);
    #pragma unroll
    for (int nt = 0; nt < 4; ++nt) {
        int col = bcol * 128 + wc * 64 + nt * 16 + l15;   // C/D: col=lane&15, row=quad*4+reg
        float bias = Bih[d * GDIM + col] + Bhh[d * GDIM + col];
        #pragma unroll
        for (int mt = 0; mt < 4; ++mt) {
            int row0 = brow * 128 + wr * 64 + mt * 16 + quad * 4;
            #pragma unroll
            for (int r = 0; r < 4; ++r)
                xgd[(size_t)(row0 + r) * GDIM + col] = f2bf(acc[mt][nt][r] + bias);
        }
    }
}

// ------------- recurrent scan (R1-proven: 234 us, VGPR 56) -------------
// 128 blocks = (d,b); 1024 threads: j = tid&255, q = tid>>8 (K-quarter).
// The compiler streams the 64 weight dwords/thread from L2 each step (bar_lds'
// "memory" clobber forces it); at 1 block/CU that is 256 KB/step through the
// ~116 B/cyc L2 return path = ~2200 cyc/step — the measured roofline for this
// decomposition. R5/R7 AGPR-residency variants were SLOWER (368-387 us): the
// accvgpr read-back tax exceeds the refetch cost. Keep the simple form.
__global__ __launch_bounds__(1024) void lstm_scan_i8(
        const u16* __restrict__ XG,        // [2][16384][1024] bf16 (this layer)
        const uint4* __restrict__ WQ,      // this layer's int8 slice
        const float* __restrict__ SCL,     // [2][1024] weight LSB
        const float* __restrict__ H0,      // [2][64][256] f32
        const float* __restrict__ C0,
        u16* __restrict__ XOUT) {          // [16384][512] bf16
    const int b   = blockIdx.x & 63;
    const int d   = blockIdx.x >> 6;
    const int tid = threadIdx.x;
    const int j   = tid & 255;
    const int q   = tid >> 8;              // K-quarter 0..3

    __shared__ uint4  hq[2][16];           // double-buffered int8 h (2 x 256 B)
    __shared__ float4 psv[4 * 256];        // per-quarter integer partials (exact f32), 16 KB

    // ---- load weights into registers (coalesced: lane-adjacent j) ----
    uint4 Wr[4][4];
    #pragma unroll
    for (int r = 0; r < 4; ++r)
        #pragma unroll
        for (int c = 0; c < 4; ++c)
            Wr[r][c] = WQ[(size_t)(((d * 4 + r) * 16 + q * 4 + c) * 256 + j)];

    float scl0 = 0.f, scl1 = 0.f, scl2 = 0.f, scl3 = 0.f, cst = 0.f;
    if (q == 0) {
        scl0 = SCL[d * GDIM + 0 * 256 + j];
        scl1 = SCL[d * GDIM + 1 * 256 + j];
        scl2 = SCL[d * GDIM + 2 * 256 + j];
        scl3 = SCL[d * GDIM + 3 * 256 + j];
        float h0v = H0[((size_t)d * BATCH + b) * HDIM + j];
        cst       = C0[((size_t)d * BATCH + b) * HDIM + j];
        int qz = (int)rintf(h0v * 31.75f);                 // scale 127/4 (|h0| can exceed 1)
        qz = qz > 127 ? 127 : (qz < -127 ? -127 : qz);
        ((signed char*)hq)[j] = (signed char)qz;           // buffer 0
    }
    __syncthreads();

    const u16* xgp = XG + (size_t)d * ((size_t)16384 * GDIM) + (size_t)b * GDIM + j;
    // even/odd register pipeline: xe used at even steps, xo at odd; reload 2 steps ahead
    u16 xe[4], xo[4];
    if (q == 0) {
        int t0 = d ? T_LEN - 1 : 0;
        int t1 = d ? T_LEN - 2 : 1;
        #pragma unroll
        for (int r = 0; r < 4; ++r) xe[r] = xgp[(size_t)t0 * (BATCH * GDIM) + r * 256];
        #pragma unroll
        for (int r = 0; r < 4; ++r) xo[r] = xgp[(size_t)t1 * (BATCH * GDIM) + r * 256];
    }

    float hs = 4.f / 127.f;                // h LSB for step 0 input h; 1/127 afterwards

#define SCAN_SUBSTEP(S, XA, RB, WB)                                                     \
    {                                                                                   \
        const int t_ = d ? (T_LEN - 1 - (S)) : (S);                                     \
        const uint4* hb = (const uint4*)hq + (RB) * 16 + q * 4;                         \
        uint4 hv[4];                                                                    \
        _Pragma("unroll")                                                               \
        for (int c = 0; c < 4; ++c) hv[c] = hb[c];          /* wave-uniform: broadcast */\
        int a0 = 0, a1 = 0, a2 = 0, a3 = 0;                                             \
        _Pragma("unroll")                                                               \
        for (int c = 0; c < 4; ++c) {                                                   \
            a0 = dot4i8(Wr[0][c].x, hv[c].x, a0);                                       \
            a0 = dot4i8(Wr[0][c].y, hv[c].y, a0);                                       \
            a0 = dot4i8(Wr[0][c].z, hv[c].z, a0);                                       \
            a0 = dot4i8(Wr[0][c].w, hv[c].w, a0);                                       \
            a1 = dot4i8(Wr[1][c].x, hv[c].x, a1);                                       \
            a1 = dot4i8(Wr[1][c].y, hv[c].y, a1);                                       \
            a1 = dot4i8(Wr[1][c].z, hv[c].z, a1);                                       \
            a1 = dot4i8(Wr[1][c].w, hv[c].w, a1);                                       \
            a2 = dot4i8(Wr[2][c].x, hv[c].x, a2);                                       \
            a2 = dot4i8(Wr[2][c].y, hv[c].y, a2);                                       \
            a2 = dot4i8(Wr[2][c].z, hv[c].z, a2);                                       \
            a2 = dot4i8(Wr[2][c].w, hv[c].w, a2);                                       \
            a3 = dot4i8(Wr[3][c].x, hv[c].x, a3);                                       \
            a3 = dot4i8(Wr[3][c].y, hv[c].y, a3);                                       \
            a3 = dot4i8(Wr[3][c].z, hv[c].z, a3);                                       \
            a3 = dot4i8(Wr[3][c].w, hv[c].w, a3);                                       \
        }                                                                               \
        /* |quarter partial| < 2^21 -> f32-exact; sums of 4 stay < 2^24 -> exact */     \
        psv[q * 256 + j] = (float4){(float)a0, (float)a1, (float)a2, (float)a3};        \
        bar_lds();                                                                      \
        if (q == 0) {                                                                   \
            float4 p0 = psv[j], p1 = psv[256 + j], p2 = psv[512 + j], p3 = psv[768 + j];\
            float g0 = bf2f(XA[0]) + (p0.x + p1.x + p2.x + p3.x) * (scl0 * hs);         \
            float g1 = bf2f(XA[1]) + (p0.y + p1.y + p2.y + p3.y) * (scl1 * hs);         \
            float g2 = bf2f(XA[2]) + (p0.z + p1.z + p2.z + p3.z) * (scl2 * hs);         \
            float g3 = bf2f(XA[3]) + (p0.w + p1.w + p2.w + p3.w) * (scl3 * hs);         \
            float iv = fsig(g0), fv = fsig(g1), gv = ftanh(g2), ov = fsig(g3);          \
            cst = fv * cst + iv * gv;                                                   \
            float h = ov * ftanh(cst);                                                  \
            XOUT[((size_t)t_ * BATCH + b) * EDIM + d * HDIM + j] = f2bf(h);             \
            int qz = (int)rintf(h * 127.f);                /* |h|<1: scale 1/127 */     \
            qz = qz > 127 ? 127 : (qz < -127 ? -127 : qz);                              \
            ((signed char*)hq)[(WB) * 256 + j] = (signed char)qz;                       \
            int s2 = ((S) + 2 < T_LEN) ? (S) + 2 : T_LEN - 1;                           \
            int t2 = d ? (T_LEN - 1 - s2) : s2;                                         \
            _Pragma("unroll")                                                           \
            for (int r = 0; r < 4; ++r)                                                 \
                XA[r] = xgp[(size_t)t2 * (BATCH * GDIM) + r * 256];                     \
        }                                                                               \
        bar_lds();                                                                      \
        hs = 1.f / 127.f;                                                               \
    }

    for (int s = 0; s < T_LEN; s += 2) {
        SCAN_SUBSTEP(s,     xe, 0, 1);
        SCAN_SUBSTEP(s + 1, xo, 1, 0);
    }
#undef SCAN_SUBSTEP
}

// ------------- feats[tb][k] = x[tb] . w_out[k] + b_out[k]  (one wave per tb) -------------
__global__ __launch_bounds__(64) void feats_k(const u16* __restrict__ X,      // [16384][512] bf16
                                              const float* __restrict__ Wout, // [7][512] f32
                                              const float* __restrict__ Bout, // [7] f32
                                              float* __restrict__ F) {        // [16384][8] f32
    int tb = blockIdx.x, lane = threadIdx.x;
    uint4 xv = ((const uint4*)(X + (size_t)tb * EDIM))[lane];   // 8 bf16 of x
    float xf[8];
    xf[0] = bflo(xv.x); xf[1] = bfhi(xv.x); xf[2] = bflo(xv.y); xf[3] = bfhi(xv.y);
    xf[4] = bflo(xv.z); xf[5] = bfhi(xv.z); xf[6] = bflo(xv.w); xf[7] = bfhi(xv.w);
    #pragma unroll
    for (int k = 0; k < KTAG; ++k) {
        const float4* wpo = (const float4*)(Wout + (size_t)k * EDIM) + lane * 2;
        float4 wa = wpo[0], wb = wpo[1];
        float p = 0.0f;
        p = fmaf(xf[0], wa.x, p); p = fmaf(xf[1], wa.y, p);
        p = fmaf(xf[2], wa.z, p); p = fmaf(xf[3], wa.w, p);
        p = fmaf(xf[4], wb.x, p); p = fmaf(xf[5], wb.y, p);
        p = fmaf(xf[6], wb.z, p); p = fmaf(xf[7], wb.w, p);
        #pragma unroll
        for (int off = 32; off > 0; off >>= 1) p += __shfl_xor(p, off, 64);
        if (lane == 0) F[tb * 8 + k] = p + Bout[k];
    }
}

// ------------- Viterbi: one wave, lane = batch; byte-packed backpointers -------------
// Backpointers stored TRANSPOSED: BPT[b][t] so the backtrace (256 dependent
// loads per lane) walks contiguous descending addresses (8 hops per 64-B line)
// instead of stride-512B scatter (one fresh L2 line per hop).
__global__ __launch_bounds__(64) void viterbi_k(const float* __restrict__ F,
                                                const float* __restrict__ Trans, // [7][7] next,prev
                                                u64* __restrict__ BPT,           // [64][256]
                                                float* __restrict__ OUT) {       // 16448 floats
    int b = threadIdx.x;
    float tr[KTAG][KTAG];
    #pragma unroll
    for (int n = 0; n < KTAG; ++n)
        #pragma unroll
        for (int p = 0; p < KTAG; ++p)
            tr[n][p] = Trans[n * KTAG + p];

    float v[KTAG];
    #pragma unroll
    for (int k = 0; k < KTAG; ++k) v[k] = (k == 5) ? 0.0f : NEGV;  // START=5

    float cf[KTAG], nf[KTAG];
    #pragma unroll
    for (int n = 0; n < KTAG; ++n) cf[n] = F[b * 8 + n];           // t=0

    for (int t = 0; t < T_LEN; ++t) {
        int tp = (t + 1 < T_LEN) ? t + 1 : t;
        #pragma unroll
        for (int n = 0; n < KTAG; ++n) nf[n] = F[((tp)*BATCH + b) * 8 + n];  // prefetch t+1

        u64 pk = 0;
        float nv[KTAG];
        #pragma unroll
        for (int n = 0; n < KTAG; ++n) {
            float best = v[0] + tr[n][0]; int bi = 0;
            #pragma unroll
            for (int p = 1; p < KTAG; ++p) {
                float s = v[p] + tr[n][p];
                if (s > best) { best = s; bi = p; }   // strict > == np.argmax first-max
            }
            pk |= ((u64)bi) << (8 * n);
            nv[n] = best + cf[n];
        }
        BPT[(b << 8) | t] = pk;
        #pragma unroll
        for (int n = 0; n < KTAG; ++n) { v[n] = nv[n]; cf[n] = nf[n]; }
    }
    float bs = v[0] + tr[6][0]; int tag = 0;          // STOP=6
    #pragma unroll
    for (int k = 1; k < KTAG; ++k) {
        float s = v[k] + tr[6][k];
        if (s > bs) { bs = s; tag = k; }
    }
    OUT[T_LEN * BATCH + b] = bs;                      // path_score [B]
    for (int t = T_LEN - 1; t >= 0; --t) {
        OUT[(size_t)b * T_LEN + t] = (float)tag;      // best_path [B][T]
        tag = (int)((BPT[(b << 8) | t] >> (8 * tag)) & 0xff);
    }
}

extern "C" void kernel_launch(void* const* d_in, const int* in_sizes, int n_in,
                              void* d_out, int out_size, void* d_ws, size_t ws_size,
                              hipStream_t stream) {
    const int*   sent  = (const int*)d_in[0];
    const float* emb   = (const float*)d_in[1];   // [50000][512]
    const float* w_ih  = (const float*)d_in[2];   // [2][2][1024][512]
    const float* w_hh  = (const float*)d_in[3];   // [2][2][1024][256]
    const float* b_ih  = (const float*)d_in[4];   // [2][2][1024]
    const float* b_hh  = (const float*)d_in[5];
    const float* w_out = (const float*)d_in[6];   // [7][512]
    const float* b_out = (const float*)d_in[7];   // [7]
    const float* trans = (const float*)d_in[8];   // [7][7]
    const float* h0    = (const float*)d_in[9];   // [4][64][256]
    const float* c0    = (const float*)d_in[10];
    float* out = (float*)d_out;

    char* ws = (char*)d_ws;
    u16*   xg    = (u16*)(ws);                       // 64 MB  [2][16384][1024] bf16
    u16*   x     = (u16*)(ws + 67108864);            // 16 MB  [16384][512] bf16
    u16*   wihB  = (u16*)(ws + 83886080);            // 4 MB   bf16 w_ih
    uint4* wq    = (uint4*)(ws + 88080384);          // 1 MB   int8 w_hh (packed)
    float* scl   = (float*)(ws + 89128960);          // 16 KB  scales
    float* feats = (float*)(ws + 89145344);          // 512 KB
    u64*   bpt   = (u64*)(ws + 89669632);            // 128 KB

    embed_k<<<16384, 64, 0, stream>>>(sent, emb, x);
    conv_wih<<<1024, 256, 0, stream>>>(w_ih, wihB);
    repack_whh_i8<<<16, 256, 0, stream>>>(w_hh, wq, scl);

    for (int l = 0; l < 2; ++l) {
        gemm_xg<<<dim3(128, 8, 2), 256, 0, stream>>>(
            x, wihB + (size_t)l * 2 * GDIM * EDIM,
            b_ih + (size_t)l * 2 * GDIM, b_hh + (size_t)l * 2 * GDIM, xg);
        // layer l's weights start at ld=2l; WQ ld-stride = 16384 uint4 -> offset l*32768
        lstm_scan_i8<<<128, 1024, 0, stream>>>(
            xg, wq + (size_t)l * 32768, scl + (size_t)l * 2048,
            h0 + (size_t)l * 2 * BATCH * HDIM, c0 + (size_t)l * 2 * BATCH * HDIM, x);
    }

    feats_k<<<16384, 64, 0, stream>>>(x, w_out, b_out, feats);
    viterbi_k<<<1, 64, 0, stream>>>(feats, trans, bpt, out);
}

// Round 9
// 822.865 us; speedup vs baseline: 1.4543x; 1.0906x over previous
//
#include <hip/hip_runtime.h>
#include <stdint.h>

#define T_LEN 256
#define BATCH 64
#define EDIM  512
#define HDIM  256      // hidden per direction
#define GDIM  1024     // 4*HDIM
#define KTAG  7
#define NEGV  -10000.0f

using u16 = unsigned short;
using u32 = unsigned int;
using u64 = unsigned long long;

typedef short    bf16x8 __attribute__((ext_vector_type(8)));
typedef float    f32x4  __attribute__((ext_vector_type(4)));

__device__ __forceinline__ float bflo(u32 u) { return __uint_as_float(u << 16); }
__device__ __forceinline__ float bfhi(u32 u) { return __uint_as_float(u & 0xffff0000u); }
__device__ __forceinline__ float bf2f(u16 u) { return __uint_as_float(((u32)u) << 16); }
__device__ __forceinline__ u16 f2bf(float f) {
    u32 x = __float_as_uint(f);
    u32 r = x + 0x7fffu + ((x >> 16) & 1u);   // round-to-nearest-even
    return (u16)(r >> 16);
}
__device__ __forceinline__ u32 pack2(float a, float b) {
    return (u32)f2bf(a) | ((u32)f2bf(b) << 16);
}
// fast sigmoid / tanh (rel err ~1e-5, far below bf16 input noise)
__device__ __forceinline__ float fsig(float x)  { return __builtin_amdgcn_rcpf(1.f + __expf(-x)); }
__device__ __forceinline__ float ftanh(float x) { return 1.f - 2.f * __builtin_amdgcn_rcpf(1.f + __expf(2.f * x)); }

__device__ __forceinline__ int dot4i8(int a, int b, int c) {
#if __has_builtin(__builtin_amdgcn_sdot4)
    return __builtin_amdgcn_sdot4(a, b, c, false);     // v_dot4_i32_i8
#else
    c += (int)(signed char)(a & 0xff)         * (int)(signed char)(b & 0xff);
    c += (int)(signed char)((a >> 8) & 0xff)  * (int)(signed char)((b >> 8) & 0xff);
    c += (int)(signed char)((a >> 16) & 0xff) * (int)(signed char)((b >> 16) & 0xff);
    c += (int)(signed char)(a >> 24)          * (int)(signed char)(b >> 24);
    return c;
#endif
}

// light barrier: order LDS only; global loads/stores stay in flight (no vmcnt drain)
__device__ __forceinline__ void bar_lds() {
    asm volatile("s_waitcnt lgkmcnt(0)" ::: "memory");
    __builtin_amdgcn_s_barrier();
    asm volatile("" ::: "memory");
}

// async global->LDS, 16B per lane; LDS dest must be linear (base + lane*16)
__device__ __forceinline__ void gload_lds16(const void* g, void* l) {
    __builtin_amdgcn_global_load_lds((const __attribute__((address_space(1))) u32*)g,
                                     (__attribute__((address_space(3))) u32*)l, 16, 0, 0);
}

// ---------------- embedding gather+convert: x[tb][e] = bf16(emb[sent[tb]][e]) ----------------
__global__ __launch_bounds__(64) void embed_k(const int* __restrict__ sent,
                                              const float* __restrict__ emb,
                                              u16* __restrict__ X) {
    int tb = blockIdx.x;
    int tok = sent[tb];
    const float4* src = (const float4*)(emb + (size_t)tok * EDIM);
    float4 a = src[threadIdx.x * 2];
    float4 b = src[threadIdx.x * 2 + 1];
    uint4 o;
    o.x = pack2(a.x, a.y); o.y = pack2(a.z, a.w);
    o.z = pack2(b.x, b.y); o.w = pack2(b.z, b.w);
    ((uint4*)(X + (size_t)tb * EDIM))[threadIdx.x] = o;
}

// ---------------- convert w_ih f32 -> bf16, same layout [2][2][1024][512] ----------------
__global__ __launch_bounds__(256) void conv_wih(const float* __restrict__ W,
                                                u16* __restrict__ WB) {
    int g = blockIdx.x * 256 + threadIdx.x;          // 262144 groups of 8
    const float4* src = (const float4*)(W + (size_t)g * 8);
    float4 a = src[0], b = src[1];
    uint4 o;
    o.x = pack2(a.x, a.y); o.y = pack2(a.z, a.w);
    o.z = pack2(b.x, b.y); o.w = pack2(b.z, b.w);
    *(uint4*)(WB + (size_t)g * 8) = o;
}

// ---- quantize w_hh f32 [4][1024][256] -> int8 WQ[((ld*4+r)*16 + c8)*256 + j] uint4 + SCL ----
// chunk c8 (0..15) of row holds k = c8*16 .. c8*16+16.  SCL[ld*1024+row] = rowmax/127.
__global__ __launch_bounds__(256) void repack_whh_i8(const float* __restrict__ Whh,
                                                     uint4* __restrict__ WQ,
                                                     float* __restrict__ SCL) {
    int g  = blockIdx.x * 256 + threadIdx.x;    // 4096 rows
    int ld = g >> 10, row = g & 1023;
    const float* src = Whh + ((size_t)ld * GDIM + row) * HDIM;
    float m = 1e-30f;
    for (int k4 = 0; k4 < 64; ++k4) {
        float4 w = ((const float4*)src)[k4];
        m = fmaxf(m, fmaxf(fmaxf(fabsf(w.x), fabsf(w.y)), fmaxf(fabsf(w.z), fabsf(w.w))));
    }
    float inv = 127.f / m;
    SCL[ld * GDIM + row] = m / 127.f;
    int r = row >> 8, j = row & 255;
    for (int c8 = 0; c8 < 16; ++c8) {           // 16-byte chunks
        u32 dw[4];
        #pragma unroll
        for (int d4 = 0; d4 < 4; ++d4) {
            u32 p = 0;
            #pragma unroll
            for (int bb = 0; bb < 4; ++bb) {
                float w = src[c8 * 16 + d4 * 4 + bb];
                int q = (int)rintf(w * inv);
                q = q > 127 ? 127 : (q < -127 ? -127 : q);
                p |= ((u32)(q & 0xff)) << (8 * bb);
            }
            dw[d4] = p;
        }
        WQ[(size_t)(((ld * 4 + r) * 16 + c8) * 256 + j)] =
            (uint4){dw[0], dw[1], dw[2], dw[3]};
    }
}

// ------------- xg = x @ w_ih^T + b_ih + b_hh -------------
// 128x128 tile, BK=64, double-buffered gload_lds staging, counted-vmcnt pipeline,
// PLUS LDS XOR-swizzle (T2 / G4): linear [row][64] u16 tiles have row stride
// 128 B = 32 banks, so a ds_read_b128's 16 l15-lanes (16 rows, same col slot)
// were a 16-way bank conflict. Fix per rule #21 (gload_lds writes linearly):
// pre-swizzle the GLOBAL source column (c8 ^= srow&7) and apply the same XOR
// on the read slot (slot ^= row&7). Pure layout permutation -> bit-identical;
// post-swizzle rows hit 8 distinct bank groups (2-way only = free).
__global__ __launch_bounds__(256, 2) void gemm_xg(const u16* __restrict__ A,    // [16384][512] bf16
                                                  const u16* __restrict__ W,    // [2][1024][512] bf16
                                                  const float* __restrict__ Bih,// [2][1024] f32
                                                  const float* __restrict__ Bhh,
                                                  u16* __restrict__ XG) {       // [2][16384][1024] bf16
    const int d    = blockIdx.z;
    const int brow = blockIdx.x;               // 0..127 (M tiles)
    const int bcol = blockIdx.y;               // 0..7   (N tiles)
    const int tid  = threadIdx.x;
    const int lane = tid & 63;
    const int wv   = tid >> 6;                 // 4 waves: 2x2 of 64x64
    const int l15  = lane & 15;
    const int quad = lane >> 4;
    const int wr   = wv >> 1, wc = wv & 1;

    __shared__ u16 As[2][128 * 64];            // 2 x 16 KB, linear dest (gload_lds)
    __shared__ u16 Bs[2][128 * 64];            // 2 x 16 KB

    const u16* Wd = W + (size_t)d * GDIM * EDIM;
    const int srow = tid >> 3;                 // staging: 32 rows / issue (it adds 32: key invariant)
    const int c8   = tid & 7;
    const int key  = srow & 7;                 // (srow + it*32)&7 == srow&7
    const int scol_g = (c8 ^ key) * 8;         // swizzled global column (u16 units)
    const u16* ga = A  + (size_t)(brow * 128 + srow) * EDIM + scol_g;
    const u16* gb = Wd + (size_t)(bcol * 128 + srow) * EDIM + scol_g;
    const int loff = srow * 64 + c8 * 8;       // linear LDS dest (= lane*8 u16)

#define STAGE(buf, kt)                                                              \
    { int k0_ = (kt) * 64;                                                          \
      _Pragma("unroll")                                                             \
      for (int it = 0; it < 4; ++it) {                                              \
          gload_lds16(ga + (size_t)(it * 32) * EDIM + k0_, &As[buf][loff + it * 32 * 64]); \
          gload_lds16(gb + (size_t)(it * 32) * EDIM + k0_, &Bs[buf][loff + it * 32 * 64]); \
      } }

    f32x4 acc[4][4];
    #pragma unroll
    for (int mt = 0; mt < 4; ++mt)
        #pragma unroll
        for (int nt = 0; nt < 4; ++nt)
            acc[mt][nt] = (f32x4){0.f, 0.f, 0.f, 0.f};

    // prologue: tiles 0 and 1 in flight (16 outstanding vmem insts per wave)
    STAGE(0, 0);
    STAGE(1, 1);

    const int rkey = l15 & 7;                  // read-side XOR key = row&7
    for (int t = 0; t < 8; ++t) {
        // wait only for tile t's 8 loads; tile t+1's 8 stay in flight
        if (t < 7) { asm volatile("s_waitcnt vmcnt(8)" ::: "memory"); }
        else       { asm volatile("s_waitcnt vmcnt(0)" ::: "memory"); }
        __builtin_amdgcn_s_barrier();

        const u16* Ab = As[t & 1];
        const u16* Bb = Bs[t & 1];
        #pragma unroll
        for (int ks = 0; ks < 2; ++ks) {
            bf16x8 av[4], bv[4];
            #pragma unroll
            for (int mt = 0; mt < 4; ++mt)
                av[mt] = *(const bf16x8*)(Ab + (wr * 64 + mt * 16 + l15) * 64
                                             + ((unsigned)(ks * 4 + quad) ^ rkey) * 8);
            #pragma unroll
            for (int nt = 0; nt < 4; ++nt)
                bv[nt] = *(const bf16x8*)(Bb + (wc * 64 + nt * 16 + l15) * 64
                                             + ((unsigned)(ks * 4 + quad) ^ rkey) * 8);
            #pragma unroll
            for (int mt = 0; mt < 4; ++mt)
                #pragma unroll
                for (int nt = 0; nt < 4; ++nt)
                    acc[mt][nt] = __builtin_amdgcn_mfma_f32_16x16x32_bf16(av[mt], bv[nt], acc[mt][nt], 0, 0, 0);
        }

        // all ds_reads of this buffer complete, then barrier, then overwrite it
        asm volatile("s_waitcnt lgkmcnt(0)" ::: "memory");
        __builtin_amdgcn_s_barrier();
        if (t < 6) STAGE(t & 1, t + 2);
    }
#undef STAGE

    u16* xgd = XG + (size_t)d * ((size_t)16384 * GDIM);
    #pragma unroll
    for (int nt = 0; nt < 4; ++nt) {
        int col = bcol * 128 + wc * 64 + nt * 16 + l15;   // C/D: col=lane&15, row=quad*4+reg
        float bias = Bih[d * GDIM + col] + Bhh[d * GDIM + col];
        #pragma unroll
        for (int mt = 0; mt < 4; ++mt) {
            int row0 = brow * 128 + wr * 64 + mt * 16 + quad * 4;
            #pragma unroll
            for (int r = 0; r < 4; ++r)
                xgd[(size_t)(row0 + r) * GDIM + col] = f2bf(acc[mt][nt][r] + bias);
        }
    }
}

// ------------- recurrent scan (R1-proven: 234 us, VGPR 56) -------------
// 128 blocks = (d,b); 1024 threads: j = tid&255, q = tid>>8 (K-quarter).
// The compiler streams the 64 weight dwords/thread from L2 each step (bar_lds'
// "memory" clobber forces it); at 1 block/CU that is 256 KB/step through the
// ~116 B/cyc L2 return path = ~2200 cyc/step — the measured roofline for this
// decomposition. R5/R7 AGPR-residency variants were SLOWER (368-387 us): the
// accvgpr read-back tax exceeds the refetch cost. Keep the simple form.
__global__ __launch_bounds__(1024) void lstm_scan_i8(
        const u16* __restrict__ XG,        // [2][16384][1024] bf16 (this layer)
        const uint4* __restrict__ WQ,      // this layer's int8 slice
        const float* __restrict__ SCL,     // [2][1024] weight LSB
        const float* __restrict__ H0,      // [2][64][256] f32
        const float* __restrict__ C0,
        u16* __restrict__ XOUT) {          // [16384][512] bf16
    const int b   = blockIdx.x & 63;
    const int d   = blockIdx.x >> 6;
    const int tid = threadIdx.x;
    const int j   = tid & 255;
    const int q   = tid >> 8;              // K-quarter 0..3

    __shared__ uint4  hq[2][16];           // double-buffered int8 h (2 x 256 B)
    __shared__ float4 psv[4 * 256];        // per-quarter integer partials (exact f32), 16 KB

    // ---- load weights into registers (coalesced: lane-adjacent j) ----
    uint4 Wr[4][4];
    #pragma unroll
    for (int r = 0; r < 4; ++r)
        #pragma unroll
        for (int c = 0; c < 4; ++c)
            Wr[r][c] = WQ[(size_t)(((d * 4 + r) * 16 + q * 4 + c) * 256 + j)];

    float scl0 = 0.f, scl1 = 0.f, scl2 = 0.f, scl3 = 0.f, cst = 0.f;
    if (q == 0) {
        scl0 = SCL[d * GDIM + 0 * 256 + j];
        scl1 = SCL[d * GDIM + 1 * 256 + j];
        scl2 = SCL[d * GDIM + 2 * 256 + j];
        scl3 = SCL[d * GDIM + 3 * 256 + j];
        float h0v = H0[((size_t)d * BATCH + b) * HDIM + j];
        cst       = C0[((size_t)d * BATCH + b) * HDIM + j];
        int qz = (int)rintf(h0v * 31.75f);                 // scale 127/4 (|h0| can exceed 1)
        qz = qz > 127 ? 127 : (qz < -127 ? -127 : qz);
        ((signed char*)hq)[j] = (signed char)qz;           // buffer 0
    }
    __syncthreads();

    const u16* xgp = XG + (size_t)d * ((size_t)16384 * GDIM) + (size_t)b * GDIM + j;
    // even/odd register pipeline: xe used at even steps, xo at odd; reload 2 steps ahead
    u16 xe[4], xo[4];
    if (q == 0) {
        int t0 = d ? T_LEN - 1 : 0;
        int t1 = d ? T_LEN - 2 : 1;
        #pragma unroll
        for (int r = 0; r < 4; ++r) xe[r] = xgp[(size_t)t0 * (BATCH * GDIM) + r * 256];
        #pragma unroll
        for (int r = 0; r < 4; ++r) xo[r] = xgp[(size_t)t1 * (BATCH * GDIM) + r * 256];
    }

    float hs = 4.f / 127.f;                // h LSB for step 0 input h; 1/127 afterwards

#define SCAN_SUBSTEP(S, XA, RB, WB)                                                     \
    {                                                                                   \
        const int t_ = d ? (T_LEN - 1 - (S)) : (S);                                     \
        const uint4* hb = (const uint4*)hq + (RB) * 16 + q * 4;                         \
        uint4 hv[4];                                                                    \
        _Pragma("unroll")                                                               \
        for (int c = 0; c < 4; ++c) hv[c] = hb[c];          /* wave-uniform: broadcast */\
        int a0 = 0, a1 = 0, a2 = 0, a3 = 0;                                             \
        _Pragma("unroll")                                                               \
        for (int c = 0; c < 4; ++c) {                                                   \
            a0 = dot4i8(Wr[0][c].x, hv[c].x, a0);                                       \
            a0 = dot4i8(Wr[0][c].y, hv[c].y, a0);                                       \
            a0 = dot4i8(Wr[0][c].z, hv[c].z, a0);                                       \
            a0 = dot4i8(Wr[0][c].w, hv[c].w, a0);                                       \
            a1 = dot4i8(Wr[1][c].x, hv[c].x, a1);                                       \
            a1 = dot4i8(Wr[1][c].y, hv[c].y, a1);                                       \
            a1 = dot4i8(Wr[1][c].z, hv[c].z, a1);                                       \
            a1 = dot4i8(Wr[1][c].w, hv[c].w, a1);                                       \
            a2 = dot4i8(Wr[2][c].x, hv[c].x, a2);                                       \
            a2 = dot4i8(Wr[2][c].y, hv[c].y, a2);                                       \
            a2 = dot4i8(Wr[2][c].z, hv[c].z, a2);                                       \
            a2 = dot4i8(Wr[2][c].w, hv[c].w, a2);                                       \
            a3 = dot4i8(Wr[3][c].x, hv[c].x, a3);                                       \
            a3 = dot4i8(Wr[3][c].y, hv[c].y, a3);                                       \
            a3 = dot4i8(Wr[3][c].z, hv[c].z, a3);                                       \
            a3 = dot4i8(Wr[3][c].w, hv[c].w, a3);                                       \
        }                                                                               \
        /* |quarter partial| < 2^21 -> f32-exact; sums of 4 stay < 2^24 -> exact */     \
        psv[q * 256 + j] = (float4){(float)a0, (float)a1, (float)a2, (float)a3};        \
        bar_lds();                                                                      \
        if (q == 0) {                                                                   \
            float4 p0 = psv[j], p1 = psv[256 + j], p2 = psv[512 + j], p3 = psv[768 + j];\
            float g0 = bf2f(XA[0]) + (p0.x + p1.x + p2.x + p3.x) * (scl0 * hs);         \
            float g1 = bf2f(XA[1]) + (p0.y + p1.y + p2.y + p3.y) * (scl1 * hs);         \
            float g2 = bf2f(XA[2]) + (p0.z + p1.z + p2.z + p3.z) * (scl2 * hs);         \
            float g3 = bf2f(XA[3]) + (p0.w + p1.w + p2.w + p3.w) * (scl3 * hs);         \
            float iv = fsig(g0), fv = fsig(g1), gv = ftanh(g2), ov = fsig(g3);          \
            cst = fv * cst + iv * gv;                                                   \
            float h = ov * ftanh(cst);                                                  \
            XOUT[((size_t)t_ * BATCH + b) * EDIM + d * HDIM + j] = f2bf(h);             \
            int qz = (int)rintf(h * 127.f);                /* |h|<1: scale 1/127 */     \
            qz = qz > 127 ? 127 : (qz < -127 ? -127 : qz);                              \
            ((signed char*)hq)[(WB) * 256 + j] = (signed char)qz;                       \
            int s2 = ((S) + 2 < T_LEN) ? (S) + 2 : T_LEN - 1;                           \
            int t2 = d ? (T_LEN - 1 - s2) : s2;                                         \
            _Pragma("unroll")                                                           \
            for (int r = 0; r < 4; ++r)                                                 \
                XA[r] = xgp[(size_t)t2 * (BATCH * GDIM) + r * 256];                     \
        }                                                                               \
        bar_lds();                                                                      \
        hs = 1.f / 127.f;                                                               \
    }

    for (int s = 0; s < T_LEN; s += 2) {
        SCAN_SUBSTEP(s,     xe, 0, 1);
        SCAN_SUBSTEP(s + 1, xo, 1, 0);
    }
#undef SCAN_SUBSTEP
}

// ------------- feats[tb][k] = x[tb] . w_out[k] + b_out[k]  (one wave per tb) -------------
__global__ __launch_bounds__(64) void feats_k(const u16* __restrict__ X,      // [16384][512] bf16
                                              const float* __restrict__ Wout, // [7][512] f32
                                              const float* __restrict__ Bout, // [7] f32
                                              float* __restrict__ F) {        // [16384][8] f32
    int tb = blockIdx.x, lane = threadIdx.x;
    uint4 xv = ((const uint4*)(X + (size_t)tb * EDIM))[lane];   // 8 bf16 of x
    float xf[8];
    xf[0] = bflo(xv.x); xf[1] = bfhi(xv.x); xf[2] = bflo(xv.y); xf[3] = bfhi(xv.y);
    xf[4] = bflo(xv.z); xf[5] = bfhi(xv.z); xf[6] = bflo(xv.w); xf[7] = bfhi(xv.w);
    #pragma unroll
    for (int k = 0; k < KTAG; ++k) {
        const float4* wpo = (const float4*)(Wout + (size_t)k * EDIM) + lane * 2;
        float4 wa = wpo[0], wb = wpo[1];
        float p = 0.0f;
        p = fmaf(xf[0], wa.x, p); p = fmaf(xf[1], wa.y, p);
        p = fmaf(xf[2], wa.z, p); p = fmaf(xf[3], wa.w, p);
        p = fmaf(xf[4], wb.x, p); p = fmaf(xf[5], wb.y, p);
        p = fmaf(xf[6], wb.z, p); p = fmaf(xf[7], wb.w, p);
        #pragma unroll
        for (int off = 32; off > 0; off >>= 1) p += __shfl_xor(p, off, 64);
        if (lane == 0) F[tb * 8 + k] = p + Bout[k];
    }
}

// ------------- Viterbi: 64 blocks (one per batch), lane n = tag state -------------
// R8's version was ONE wave doing the whole 7x7 recurrence per lane (~210 VALU
// insts/step x 256 steps on 1 SIMD of 1 CU ~= 60-80 us). Now lane n owns state
// n: per step each lane does 7 shfl (v-exchange) + 7 add + 6 cmp (~35 insts),
// and 64 blocks run in parallel. Ascending-p strict-> first-max semantics kept
// identical; byte-packed BPT[b][t] layout identical -> same path, same score.
__global__ __launch_bounds__(64) void viterbi_k(const float* __restrict__ F,
                                                const float* __restrict__ Trans, // [7][7] next,prev
                                                u64* __restrict__ BPT,           // [64][256]
                                                float* __restrict__ OUT) {       // 16448 floats
    const int b  = blockIdx.x;            // one block per batch element
    const int n  = threadIdx.x;           // lanes 0..6 = tag states; 7..63 spectators
    const int nn = (n < KTAG) ? n : 0;    // clamp for safe loads

    float trn[KTAG];                      // tr[n][p]: into-state-n row
    #pragma unroll
    for (int p = 0; p < KTAG; ++p) trn[p] = Trans[nn * KTAG + p];
    const float t6n = Trans[6 * KTAG + nn];   // STOP row entry for state n

    float v  = (nn == 5) ? 0.0f : NEGV;       // START=5 (lane 5 holds 0)
    float cf = F[(size_t)b * 8 + nn];         // feat t=0, state n

    for (int t = 0; t < T_LEN; ++t) {
        int tp = (t + 1 < T_LEN) ? t + 1 : t;
        float nf = F[((size_t)tp * BATCH + b) * 8 + nn];   // prefetch t+1

        float vp[KTAG];
        #pragma unroll
        for (int p = 0; p < KTAG; ++p) vp[p] = __shfl(v, p, 64);

        float best = vp[0] + trn[0]; int bi = 0;
        #pragma unroll
        for (int p = 1; p < KTAG; ++p) {
            float s = vp[p] + trn[p];
            if (s > best) { best = s; bi = p; }   // strict > == np.argmax first-max
        }
        u64 pk = 0;
        #pragma unroll
        for (int p = 0; p < KTAG; ++p)
            pk |= ((u64)(u32)__shfl(bi, p, 64)) << (8 * p);
        if (n == 0) BPT[(b << 8) | t] = pk;

        v  = best + cf;
        cf = nf;
    }

    float term = v + t6n;
    float tv[KTAG];
    #pragma unroll
    for (int k = 0; k < KTAG; ++k) tv[k] = __shfl(term, k, 64);
    if (n == 0) {
        float bs = tv[0]; int tag = 0;
        #pragma unroll
        for (int k = 1; k < KTAG; ++k)
            if (tv[k] > bs) { bs = tv[k]; tag = k; }
        OUT[T_LEN * BATCH + b] = bs;                  // path_score [B]
        for (int t = T_LEN - 1; t >= 0; --t) {
            OUT[(size_t)b * T_LEN + t] = (float)tag;  // best_path [B][T]
            tag = (int)((BPT[(b << 8) | t] >> (8 * tag)) & 0xff);
        }
    }
}

extern "C" void kernel_launch(void* const* d_in, const int* in_sizes, int n_in,
                              void* d_out, int out_size, void* d_ws, size_t ws_size,
                              hipStream_t stream) {
    const int*   sent  = (const int*)d_in[0];
    const float* emb   = (const float*)d_in[1];   // [50000][512]
    const float* w_ih  = (const float*)d_in[2];   // [2][2][1024][512]
    const float* w_hh  = (const float*)d_in[3];   // [2][2][1024][256]
    const float* b_ih  = (const float*)d_in[4];   // [2][2][1024]
    const float* b_hh  = (const float*)d_in[5];
    const float* w_out = (const float*)d_in[6];   // [7][512]
    const float* b_out = (const float*)d_in[7];   // [7]
    const float* trans = (const float*)d_in[8];   // [7][7]
    const float* h0    = (const float*)d_in[9];   // [4][64][256]
    const float* c0    = (const float*)d_in[10];
    float* out = (float*)d_out;

    char* ws = (char*)d_ws;
    u16*   xg    = (u16*)(ws);                       // 64 MB  [2][16384][1024] bf16
    u16*   x     = (u16*)(ws + 67108864);            // 16 MB  [16384][512] bf16
    u16*   wihB  = (u16*)(ws + 83886080);            // 4 MB   bf16 w_ih
    uint4* wq    = (uint4*)(ws + 88080384);          // 1 MB   int8 w_hh (packed)
    float* scl   = (float*)(ws + 89128960);          // 16 KB  scales
    float* feats = (float*)(ws + 89145344);          // 512 KB
    u64*   bpt   = (u64*)(ws + 89669632);            // 128 KB

    embed_k<<<16384, 64, 0, stream>>>(sent, emb, x);
    conv_wih<<<1024, 256, 0, stream>>>(w_ih, wihB);
    repack_whh_i8<<<16, 256, 0, stream>>>(w_hh, wq, scl);

    for (int l = 0; l < 2; ++l) {
        gemm_xg<<<dim3(128, 8, 2), 256, 0, stream>>>(
            x, wihB + (size_t)l * 2 * GDIM * EDIM,
            b_ih + (size_t)l * 2 * GDIM, b_hh + (size_t)l * 2 * GDIM, xg);
        // layer l's weights start at ld=2l; WQ ld-stride = 16384 uint4 -> offset l*32768
        lstm_scan_i8<<<128, 1024, 0, stream>>>(
            xg, wq + (size_t)l * 32768, scl + (size_t)l * 2048,
            h0 + (size_t)l * 2 * BATCH * HDIM, c0 + (size_t)l * 2 * BATCH * HDIM, x);
    }

    feats_k<<<16384, 64, 0, stream>>>(x, w_out, b_out, feats);
    viterbi_k<<<64, 64, 0, stream>>>(feats, trans, bpt, out);
}